// Round 3
// baseline (30138.956 us; speedup 1.0000x reference)
//
#include <hip/hip_runtime.h>
#include <math.h>

#define BATCH 64
#define TT 256
#define IN_DIM 512
#define H 1024
#define NBLK 256
#define HB_STRIDE (H * BATCH)
#define SMEM_FLOATS (32768 + 4096 + 16)
#define SMEM_BYTES (SMEM_FLOATS * 4)

// ---------------------------------------------------------------------------
__global__ void zero_kernel(float* __restrict__ p, int n) {
    int i = blockIdx.x * 256 + threadIdx.x;
    if (i < n) p[i] = 0.f;
}

__device__ __forceinline__ float sigm(float v) { return 1.f / (1.f + __expf(-v)); }
__device__ __forceinline__ float tanhf_(float v) {
    float e = __expf(-2.f * fabsf(v));
    float r = (1.f - e) / (1.f + e);
    return v < 0.f ? -r : r;
}

// ---------------------------------------------------------------------------
// Persistent 2-layer LSTM. 256 blocks (1/CU, forced by 144KB LDS), 256 thr.
// Block owns 4 hidden units = 16 gate rows. W slice resident in LDS
// (k-major, (k>>2)-rotated float4 chunks -> <=2-way bank conflicts).
// Thread tile: 16 rows x 8 batch, k split 32-way across (wave, ks-lanes).
// Grid barrier: per-step device-scope atomic counter + fences.
__global__ __launch_bounds__(256, 1) void lstm_persistent(
    const float* __restrict__ x,
    const float* __restrict__ Wih0, const float* __restrict__ Whh0, const float* __restrict__ b0,
    const float* __restrict__ Wih1, const float* __restrict__ Whh1, const float* __restrict__ b1,
    float* __restrict__ ys, float* __restrict__ hbuf, const float* __restrict__ hzero,
    int* __restrict__ ctr)
{
    extern __shared__ float sm[];
    float* Wlds = sm;                 // [K][16] rotated, up to 2048*16
    float* scr  = sm + 32768;         // [4 waves][16 r][64 b]
    float* bls  = sm + 32768 + 4096;  // [16]

    const int tid = threadIdx.x;
    const int bid = blockIdx.x;
    const int w  = tid >> 6;          // wave 0..3
    const int ks = (tid >> 3) & 7;    // k-sub-slice within wave
    const int bg = tid & 7;           // batch group (8 b each)
    const int s  = w * 8 + ks;        // global k-slice 0..31
    const int rot = s & 3;            // == (k>>2)&3 for this thread's k
    const int j4 = bid * 4;
    const int eu = tid >> 6;          // epilogue: unit 0..3
    const int eb = tid & 63;          // epilogue: batch

    float c_state = 0.f;

    for (int layer = 0; layer < 2; ++layer) {
        const int Kx   = layer ? H : IN_DIM;
        const int NKB  = (Kx + H) >> 7;   // 12 or 16 (even)
        const int NKBX = Kx >> 7;         // 4 or 8
        const float* Wih  = layer ? Wih1 : Wih0;
        const float* Whh  = layer ? Whh1 : Whh0;
        const float* bias = layer ? b1 : b0;

        // ---- stage W slice into LDS (transposed k-major + rotation) ----
        for (int r = 0; r < 16; ++r) {
            const float* srcA = Wih + (size_t)((r >> 2) * H + j4 + (r & 3)) * Kx;
            const float* srcB = Whh + (size_t)((r >> 2) * H + j4 + (r & 3)) * H;
            for (int k4 = tid * 4; k4 < Kx + H; k4 += 1024) {
                float4 v = (k4 < Kx) ? *(const float4*)(srcA + k4)
                                     : *(const float4*)(srcB + (k4 - Kx));
#pragma unroll
                for (int i = 0; i < 4; ++i) {
                    int k = k4 + i;
                    Wlds[k * 16 + (((r >> 2) + (k >> 2)) & 3) * 4 + (r & 3)] = (&v.x)[i];
                }
            }
        }
        if (tid < 16) bls[tid] = bias[(tid >> 2) * H + j4 + (tid & 3)];
        c_state = 0.f;
        __syncthreads();

        for (int t = 0; t < TT; ++t) {
            const float* srch = (t == 0) ? hzero : (hbuf + ((t & 1) ? HB_STRIDE : 0));
            float* hw = hbuf + (((t + 1) & 1) ? HB_STRIDE : 0);
            const float* srcy = ys + (size_t)t * HB_STRIDE;
            const float* xt = x + (size_t)t * IN_DIM;

            float acc[16][8];
#pragma unroll
            for (int r = 0; r < 16; ++r)
#pragma unroll
                for (int j = 0; j < 8; ++j) acc[r][j] = 0.f;

            float bufA[4][8], bufB[4][8];

            auto load_kb = [&](int kb, float (&B)[4][8]) {
                const int k0 = kb * 128 + s * 4;
                if (kb < NKBX) {
                    if (layer == 0) {
                        // x: [b][t][k] row-major; float4 along k, transpose to B
#pragma unroll
                        for (int j = 0; j < 8; ++j) {
                            float4 v = *(const float4*)(xt + (size_t)(bg * 8 + j) * (TT * IN_DIM) + k0);
                            B[0][j] = v.x; B[1][j] = v.y; B[2][j] = v.z; B[3][j] = v.w;
                        }
                    } else {
                        const float* base = srcy + (size_t)k0 * BATCH + bg * 8;
#pragma unroll
                        for (int kk = 0; kk < 4; ++kk) {
                            *(float4*)&B[kk][0] = *(const float4*)(base + kk * BATCH);
                            *(float4*)&B[kk][4] = *(const float4*)(base + kk * BATCH + 4);
                        }
                    }
                } else {
                    const float* base = srch + (size_t)(k0 - Kx) * BATCH + bg * 8;
#pragma unroll
                    for (int kk = 0; kk < 4; ++kk) {
                        *(float4*)&B[kk][0] = *(const float4*)(base + kk * BATCH);
                        *(float4*)&B[kk][4] = *(const float4*)(base + kk * BATCH + 4);
                    }
                }
            };

            auto comp_kb = [&](int kb, const float (&B)[4][8]) {
                const int k0 = kb * 128 + s * 4;
#pragma unroll
                for (int kk = 0; kk < 4; ++kk) {
                    const float* wp = Wlds + (k0 + kk) * 16;
                    float4 w0 = *(const float4*)(wp + ((0 + rot) & 3) * 4);
                    float4 w1 = *(const float4*)(wp + ((1 + rot) & 3) * 4);
                    float4 w2 = *(const float4*)(wp + ((2 + rot) & 3) * 4);
                    float4 w3 = *(const float4*)(wp + ((3 + rot) & 3) * 4);
#pragma unroll
                    for (int j = 0; j < 8; ++j) {
                        float hv = B[kk][j];
                        acc[0][j]  += w0.x * hv;  acc[1][j]  += w0.y * hv;
                        acc[2][j]  += w0.z * hv;  acc[3][j]  += w0.w * hv;
                        acc[4][j]  += w1.x * hv;  acc[5][j]  += w1.y * hv;
                        acc[6][j]  += w1.z * hv;  acc[7][j]  += w1.w * hv;
                        acc[8][j]  += w2.x * hv;  acc[9][j]  += w2.y * hv;
                        acc[10][j] += w2.z * hv;  acc[11][j] += w2.w * hv;
                        acc[12][j] += w3.x * hv;  acc[13][j] += w3.y * hv;
                        acc[14][j] += w3.z * hv;  acc[15][j] += w3.w * hv;
                    }
                }
            };

            // software-pipelined k-block loop (NKB is even)
            load_kb(0, bufA);
            for (int kb = 0; kb < NKB; kb += 2) {
                load_kb(kb + 1, bufB);
                comp_kb(kb, bufA);
                if (kb + 2 < NKB) load_kb(kb + 2, bufA);
                comp_kb(kb + 1, bufB);
            }

            // ---- reduce over ks (lane bits 3..5) ----
#pragma unroll
            for (int r = 0; r < 16; ++r)
#pragma unroll
                for (int j = 0; j < 8; ++j) {
                    float v = acc[r][j];
                    v += __shfl_xor(v, 8, 64);
                    v += __shfl_xor(v, 16, 64);
                    v += __shfl_xor(v, 32, 64);
                    acc[r][j] = v;
                }
            if (ks == 0) {
#pragma unroll
                for (int r = 0; r < 16; ++r) {
                    float4 v0 = make_float4(acc[r][0], acc[r][1], acc[r][2], acc[r][3]);
                    float4 v1 = make_float4(acc[r][4], acc[r][5], acc[r][6], acc[r][7]);
                    *(float4*)&scr[(w * 16 + r) * 64 + bg * 8] = v0;
                    *(float4*)&scr[(w * 16 + r) * 64 + bg * 8 + 4] = v1;
                }
            }
            __syncthreads();

            // ---- epilogue: gates -> activations -> h,c ----
            {
                float gg[4];
#pragma unroll
                for (int gi = 0; gi < 4; ++gi) {
                    int r = gi * 4 + eu;
                    gg[gi] = scr[r * 64 + eb] + scr[(16 + r) * 64 + eb]
                           + scr[(32 + r) * 64 + eb] + scr[(48 + r) * 64 + eb] + bls[r];
                }
                float is = sigm(gg[0]);
                float fs = sigm(gg[1]);
                float gt = tanhf_(gg[2]);
                float os = sigm(gg[3]);
                c_state = fs * c_state + is * gt;
                float hnew = os * tanhf_(c_state);
                hw[(j4 + eu) * BATCH + eb] = hnew;
                if (layer == 0) ys[((size_t)t * H + j4 + eu) * BATCH + eb] = hnew;
            }

            // ---- grid barrier (device-scope) ----
            __syncthreads();   // drains vmcnt for all waves (HIP semantics)
            if (tid == 0) {
                const int bidx = layer * TT + t;
                __builtin_amdgcn_fence(__ATOMIC_RELEASE, "agent");
                __hip_atomic_fetch_add(&ctr[bidx], 1, __ATOMIC_RELEASE, __HIP_MEMORY_SCOPE_AGENT);
                while (__hip_atomic_load(&ctr[bidx], __ATOMIC_ACQUIRE, __HIP_MEMORY_SCOPE_AGENT) < NBLK)
                    __builtin_amdgcn_s_sleep(8);
                __builtin_amdgcn_fence(__ATOMIC_ACQUIRE, "agent");
            }
            __syncthreads();
        }
    }
}

// ---------------------------------------------------------------------------
// out[b][o] = sum_j h[j][b] * Wfc[o][j] + bfc[o]   (h_last at hbuf offset 0)
__global__ __launch_bounds__(256) void fc_kernel(
    const float* __restrict__ hT, const float* __restrict__ Wfc,
    const float* __restrict__ bfc, float* __restrict__ out) {
    int tid = threadIdx.x;
    int b = tid & 63;
    int oo = __builtin_amdgcn_readfirstlane(tid >> 6);
    int o = blockIdx.x * 4 + oo;
    const float* wr = Wfc + (size_t)o * H;
    float acc = 0.f;
#pragma unroll 8
    for (int j = 0; j < H; j += 4) {
        float4 wv = *(const float4*)(wr + j);
        acc += hT[(size_t)(j + 0) * BATCH + b] * wv.x
             + hT[(size_t)(j + 1) * BATCH + b] * wv.y
             + hT[(size_t)(j + 2) * BATCH + b] * wv.z
             + hT[(size_t)(j + 3) * BATCH + b] * wv.w;
    }
    out[(size_t)b * 512 + o] = acc + bfc[o];
}

// ---------------------------------------------------------------------------
extern "C" void kernel_launch(void* const* d_in, const int* in_sizes, int n_in,
                              void* d_out, int out_size, void* d_ws, size_t ws_size,
                              hipStream_t stream) {
    const float* x    = (const float*)d_in[0];
    const float* Wih0 = (const float*)d_in[1];
    const float* Whh0 = (const float*)d_in[2];
    const float* b0   = (const float*)d_in[3];
    const float* Wih1 = (const float*)d_in[4];
    const float* Whh1 = (const float*)d_in[5];
    const float* b1   = (const float*)d_in[6];
    const float* Wfc  = (const float*)d_in[7];
    const float* bfc  = (const float*)d_in[8];
    float* out = (float*)d_out;

    // ws: ys[256][1024][64] | hbuf[2][1024][64] | hzero[1024][64] | ctr[1024]
    float* ys    = (float*)d_ws;
    float* hbuf  = ys + (size_t)TT * H * BATCH;
    float* hzero = hbuf + 2 * HB_STRIDE;
    int*   ctr   = (int*)(hzero + HB_STRIDE);

    int zn = HB_STRIDE + 1024;  // hzero + ctr region
    zero_kernel<<<(zn + 255) / 256, 256, 0, stream>>>(hzero, zn);

    hipFuncSetAttribute((const void*)lstm_persistent,
                        hipFuncAttributeMaxDynamicSharedMemorySize, SMEM_BYTES);
    lstm_persistent<<<NBLK, 256, SMEM_BYTES, stream>>>(
        x, Wih0, Whh0, b0, Wih1, Whh1, b1, ys, hbuf, hzero, ctr);

    fc_kernel<<<128, 256, 0, stream>>>(hbuf, Wfc, bfc, out);
}

// Round 4
// 11486.340 us; speedup vs baseline: 2.6239x; 2.6239x over previous
//
#include <hip/hip_runtime.h>
#include <math.h>

#define BATCH 64
#define TT 256
#define IN_DIM 512
#define H 1024
#define RECBLK 128

typedef __attribute__((ext_vector_type(8))) _Float16 f16x8;
typedef __attribute__((ext_vector_type(4))) _Float16 f16x4;
typedef __attribute__((ext_vector_type(4))) float f32x4;

#define MFMA16 __builtin_amdgcn_mfma_f32_16x16x32_f16

__device__ __forceinline__ float sigm(float v) { return 1.f / (1.f + __expf(-v)); }
__device__ __forceinline__ float tanhf_(float v) {
    float e = __expf(-2.f * fabsf(v));
    float r = (1.f - e) / (1.f + e);
    return v < 0.f ? -r : r;
}
__device__ __forceinline__ void split16(float v, _Float16& hi, _Float16& lo) {
    hi = (_Float16)v;
    lo = (_Float16)((v - (float)hi) * 2048.0f);
}
// fragment index for value (j in [0,1024), b in [0,64)) within one 65536-elem timestep frag
__device__ __forceinline__ int fidx(int j, int b) {
    int c = j >> 5, kin = j & 31;
    int l = (b & 15) + ((kin >> 3) << 4);
    int n = b >> 4;
    return (((c * 4 + n) * 64) + l) * 8 + (kin & 7);
}

// ---------------------------------------------------------------------------
__global__ void zero_kernel(float* __restrict__ p, int n) {
    int i = blockIdx.x * 256 + threadIdx.x;
    if (i < n) p[i] = 0.f;
}

// ---------------------------------------------------------------------------
// transpose+split x[b][t][k] fp32 -> xstage frags (seg-local t), 16 chunks (K=512)
__global__ __launch_bounds__(256) void xT_kernel(
    const float* __restrict__ x, _Float16* __restrict__ xh, _Float16* __restrict__ xl, int t0) {
    const int tid = threadIdx.x;
    const int n = tid >> 6, l = tid & 63;
    const int ti = blockIdx.x >> 4, c = blockIdx.x & 15;
    const int b = n * 16 + (l & 15);
    const int k = c * 32 + (l >> 4) * 8;
    const float* src = x + ((size_t)b * TT + t0 + ti) * IN_DIM + k;
    float4 v0 = *(const float4*)src;
    float4 v1 = *(const float4*)(src + 4);
    float tmp[8] = {v0.x, v0.y, v0.z, v0.w, v1.x, v1.y, v1.z, v1.w};
    f16x8 hi, lo;
#pragma unroll
    for (int e = 0; e < 8; ++e) { _Float16 h_, l_; split16(tmp[e], h_, l_); hi[e] = h_; lo[e] = l_; }
    size_t o = (((size_t)ti * 16 + c) * 4 + n) * 512 + l * 8;
    *(f16x8*)(xh + o) = hi;
    *(f16x8*)(xl + o) = lo;
}

// ---------------------------------------------------------------------------
// xp GEMM: xpseg[ti][r'][b] = sum_k W[r'][k] * B(t,b,k) + bias[r']
// r' = 4*j + g permutation (W row = g*H + j). A staged into LDS split f16
// (XOR-swizzled), B from frag-layout f16 arrays (xstage or ysfrag).
template<int LAYER>
__global__ __launch_bounds__(256, 1) void xp_gemm(
    const float* __restrict__ Wih, const float* __restrict__ bias,
    const _Float16* __restrict__ Bhi, const _Float16* __restrict__ Blo,
    float* __restrict__ xpseg, int t0) {
    const int K = LAYER ? 1024 : 512;
    __shared__ _Float16 AhiL[64 * 64];
    __shared__ _Float16 AloL[64 * 64];
    const int tid = threadIdx.x, l = tid & 63, w = tid >> 6;
    const int mbase = blockIdx.x * 64;
    const int tiloc = blockIdx.y * 4 + w;  // seg-local timestep
    const int arow = l & 15, akg = l >> 4;

    f32x4 ah[4][4], al[4][4];
#pragma unroll
    for (int m = 0; m < 4; ++m)
#pragma unroll
        for (int ns = 0; ns < 4; ++ns) { ah[m][ns] = (f32x4){0.f,0.f,0.f,0.f}; al[m][ns] = (f32x4){0.f,0.f,0.f,0.f}; }

    for (int kb = 0; kb < K / 64; ++kb) {
        // stage A tile (64 rows x 64 k) split into LDS
#pragma unroll
        for (int i = 0; i < 4; ++i) {
            int idx = tid + i * 256;
            int r = idx >> 4, kc = (idx & 15) * 4;
            int rp = mbase + r;
            const float* src = Wih + (size_t)((rp & 3) * H + (rp >> 2)) * K + kb * 64 + kc;
            float4 v = *(const float4*)src;
            int base = (r * 64 + kc) ^ ((r & 7) << 3);
            _Float16 h0, l0, h1, l1, h2, l2, h3, l3;
            split16(v.x, h0, l0); split16(v.y, h1, l1);
            split16(v.z, h2, l2); split16(v.w, h3, l3);
            *(f16x4*)&AhiL[base] = (f16x4){h0, h1, h2, h3};
            *(f16x4*)&AloL[base] = (f16x4){l0, l1, l2, l3};
        }
        __syncthreads();
#pragma unroll
        for (int c = 0; c < 2; ++c) {
            f16x8 Af[4], Afl[4];
#pragma unroll
            for (int m = 0; m < 4; ++m) {
                int row = m * 16 + arow;
                int ei = (row * 64 + c * 32 + akg * 8) ^ ((row & 7) << 3);
                Af[m] = *(const f16x8*)&AhiL[ei];
                Afl[m] = *(const f16x8*)&AloL[ei];
            }
            int cg = kb * 2 + c;
#pragma unroll
            for (int ns = 0; ns < 4; ++ns) {
                size_t boff;
                if (LAYER)
                    boff = (((size_t)(t0 + tiloc) * 32 + cg) * 4 + ns) * 512 + l * 8;
                else
                    boff = (((size_t)tiloc * 16 + cg) * 4 + ns) * 512 + l * 8;
                f16x8 bh = *(const f16x8*)(Bhi + boff);
                f16x8 bl = *(const f16x8*)(Blo + boff);
#pragma unroll
                for (int m = 0; m < 4; ++m) {
                    ah[m][ns] = MFMA16(Af[m], bh, ah[m][ns], 0, 0, 0);
                    al[m][ns] = MFMA16(Af[m], bl, al[m][ns], 0, 0, 0);
                    al[m][ns] = MFMA16(Afl[m], bh, al[m][ns], 0, 0, 0);
                }
            }
        }
        __syncthreads();
    }
    // epilogue: D row = m*16 + akg*4 + reg, col b = ns*16 + arow
#pragma unroll
    for (int m = 0; m < 4; ++m) {
#pragma unroll
        for (int r = 0; r < 4; ++r) {
            int rp = mbase + m * 16 + akg * 4 + r;
            float bv = bias[(rp & 3) * H + (rp >> 2)];
#pragma unroll
            for (int ns = 0; ns < 4; ++ns) {
                float v = ah[m][ns][r] + al[m][ns][r] * (1.f / 2048.f) + bv;
                xpseg[((size_t)tiloc * 4096 + rp) * 64 + ns * 16 + arow] = v;
            }
        }
    }
}

// ---------------------------------------------------------------------------
// Recurrence: 128 blocks x 256 thr, seg steps per launch. Block owns 32 gate
// rows (8 units). W fragments live in VGPRs (split f16). h exchanged via
// frag-layout global arrays; device-scope atomic barrier per step.
__global__ __launch_bounds__(256, 1) void rec_kernel(
    const float* __restrict__ Whh, const float* __restrict__ xpseg,
    _Float16* __restrict__ hfh, _Float16* __restrict__ hfl,
    _Float16* __restrict__ ysh, _Float16* __restrict__ ysl,
    float* __restrict__ cT, int* __restrict__ ctr, int t0, int seg, int layer) {
    __shared__ float scr[4][32][65];
    const int tid = threadIdx.x;
    const int bid = blockIdx.x;
    const int l = tid & 63;
    const int w = tid >> 6;
    const int arow = l & 15, akg = l >> 4;

    // ---- load + split A (W) fragments into VGPRs: wave w owns k in [w*256, w*256+256)
    f16x8 Ah[2][8], Al[2][8];
#pragma unroll
    for (int m = 0; m < 2; ++m) {
#pragma unroll
        for (int c = 0; c < 8; ++c) {
            int rp = bid * 32 + m * 16 + arow;
            int k = w * 256 + c * 32 + akg * 8;
            const float* src = Whh + (size_t)((rp & 3) * H + (rp >> 2)) * H + k;
            float4 v0 = *(const float4*)src;
            float4 v1 = *(const float4*)(src + 4);
            float tmp[8] = {v0.x, v0.y, v0.z, v0.w, v1.x, v1.y, v1.z, v1.w};
            f16x8 hi, lo;
#pragma unroll
            for (int e = 0; e < 8; ++e) { _Float16 h_, l_; split16(tmp[e], h_, l_); hi[e] = h_; lo[e] = l_; }
            Ah[m][c] = hi; Al[m][c] = lo;
        }
    }
    // ---- c state (2 slots/thread)
    const int u0 = tid >> 6, eb = tid & 63;
    float cs0 = cT[(size_t)(bid * 8 + u0) * 64 + eb];
    float cs1 = cT[(size_t)(bid * 8 + u0 + 4) * 64 + eb];

    for (int t = t0; t < t0 + seg; ++t) {
        const _Float16* bh = hfh + (size_t)(t & 1) * 65536;
        const _Float16* bl = hfl + (size_t)(t & 1) * 65536;
        f32x4 ah[2][4], al2[2][4];
#pragma unroll
        for (int m = 0; m < 2; ++m)
#pragma unroll
            for (int ns = 0; ns < 4; ++ns) { ah[m][ns] = (f32x4){0.f,0.f,0.f,0.f}; al2[m][ns] = (f32x4){0.f,0.f,0.f,0.f}; }

        f16x8 Bh[2][4], Bl[2][4];
        {
            int ch = w * 8;
#pragma unroll
            for (int ns = 0; ns < 4; ++ns) {
                Bh[0][ns] = *(const f16x8*)(bh + (size_t)(ch * 4 + ns) * 512 + l * 8);
                Bl[0][ns] = *(const f16x8*)(bl + (size_t)(ch * 4 + ns) * 512 + l * 8);
            }
        }
#pragma unroll
        for (int c = 0; c < 8; ++c) {
            const int cur = c & 1;
            if (c < 7) {
                int ch = w * 8 + c + 1;
#pragma unroll
                for (int ns = 0; ns < 4; ++ns) {
                    Bh[cur ^ 1][ns] = *(const f16x8*)(bh + (size_t)(ch * 4 + ns) * 512 + l * 8);
                    Bl[cur ^ 1][ns] = *(const f16x8*)(bl + (size_t)(ch * 4 + ns) * 512 + l * 8);
                }
            }
#pragma unroll
            for (int ns = 0; ns < 4; ++ns) {
#pragma unroll
                for (int m = 0; m < 2; ++m) {
                    ah[m][ns] = MFMA16(Ah[m][c], Bh[cur][ns], ah[m][ns], 0, 0, 0);
                    al2[m][ns] = MFMA16(Ah[m][c], Bl[cur][ns], al2[m][ns], 0, 0, 0);
                    al2[m][ns] = MFMA16(Al[m][c], Bh[cur][ns], al2[m][ns], 0, 0, 0);
                }
            }
        }
        // ---- partial-K reduce via LDS
#pragma unroll
        for (int m = 0; m < 2; ++m)
#pragma unroll
            for (int ns = 0; ns < 4; ++ns)
#pragma unroll
                for (int r = 0; r < 4; ++r)
                    scr[w][m * 16 + akg * 4 + r][ns * 16 + arow] =
                        ah[m][ns][r] + al2[m][ns][r] * (1.f / 2048.f);
        __syncthreads();

        // ---- epilogue: 2 slots per thread: (u0,eb) and (u0+4,eb)
        float g0[4], g1[4];
#pragma unroll
        for (int g = 0; g < 4; ++g) {
            int r0 = u0 * 4 + g, r1 = (u0 + 4) * 4 + g;
            g0[g] = scr[0][r0][eb] + scr[1][r0][eb] + scr[2][r0][eb] + scr[3][r0][eb]
                  + xpseg[((size_t)(t - t0) * 4096 + bid * 32 + r0) * 64 + eb];
            g1[g] = scr[0][r1][eb] + scr[1][r1][eb] + scr[2][r1][eb] + scr[3][r1][eb]
                  + xpseg[((size_t)(t - t0) * 4096 + bid * 32 + r1) * 64 + eb];
        }
        float i0 = sigm(g0[0]), f0 = sigm(g0[1]), gg0 = tanhf_(g0[2]), o0 = sigm(g0[3]);
        cs0 = f0 * cs0 + i0 * gg0;
        float h0v = o0 * tanhf_(cs0);
        float i1 = sigm(g1[0]), f1 = sigm(g1[1]), gg1 = tanhf_(g1[2]), o1 = sigm(g1[3]);
        cs1 = f1 * cs1 + i1 * gg1;
        float h1v = o1 * tanhf_(cs1);

        {
            _Float16 hh, hl;
            int j0 = bid * 8 + u0, j1 = j0 + 4;
            int i0f = fidx(j0, eb), i1f = fidx(j1, eb);
            size_t so = (size_t)((t + 1) & 1) * 65536;
            split16(h0v, hh, hl);
            hfh[so + i0f] = hh; hfl[so + i0f] = hl;
            if (layer == 0) { ysh[(size_t)t * 65536 + i0f] = hh; ysl[(size_t)t * 65536 + i0f] = hl; }
            split16(h1v, hh, hl);
            hfh[so + i1f] = hh; hfl[so + i1f] = hl;
            if (layer == 0) { ysh[(size_t)t * 65536 + i1f] = hh; ysl[(size_t)t * 65536 + i1f] = hl; }
        }

        // ---- grid barrier (skip after last step; launch boundary orders it)
        __syncthreads();
        if (t != t0 + seg - 1) {
            if (tid == 0) {
                const int bidx = layer * 256 + t;
                __builtin_amdgcn_fence(__ATOMIC_RELEASE, "agent");
                __hip_atomic_fetch_add(&ctr[bidx], 1, __ATOMIC_RELEASE, __HIP_MEMORY_SCOPE_AGENT);
                while (__hip_atomic_load(&ctr[bidx], __ATOMIC_ACQUIRE, __HIP_MEMORY_SCOPE_AGENT) < RECBLK)
                    __builtin_amdgcn_s_sleep(4);
                __builtin_amdgcn_fence(__ATOMIC_ACQUIRE, "agent");
            }
            __syncthreads();
        }
    }
    cT[(size_t)(bid * 8 + u0) * 64 + eb] = cs0;
    cT[(size_t)(bid * 8 + u0 + 4) * 64 + eb] = cs1;
}

// ---------------------------------------------------------------------------
// out[b][o] = sum_j h[j][b] * Wfc[o][j] + bfc[o], h from frag slot 0
__global__ __launch_bounds__(256) void fc_kernel(
    const _Float16* __restrict__ hh, const _Float16* __restrict__ hl,
    const float* __restrict__ Wfc, const float* __restrict__ bfc, float* __restrict__ out) {
    const int tid = threadIdx.x;
    const int b = tid & 63;
    const int o = blockIdx.x * 4 + (tid >> 6);
    const float* wr = Wfc + (size_t)o * H;
    float acc = 0.f;
    for (int jb = 0; jb < 128; ++jb) {
        int j = jb * 8;
        int idx = fidx(j, b);
        f16x8 vh = *(const f16x8*)(hh + idx);
        f16x8 vl = *(const f16x8*)(hl + idx);
#pragma unroll
        for (int e = 0; e < 8; ++e) {
            float hv = (float)vh[e] + (float)vl[e] * (1.f / 2048.f);
            acc += hv * wr[j + e];
        }
    }
    out[(size_t)b * 512 + o] = acc + bfc[o];
}

// ---------------------------------------------------------------------------
extern "C" void kernel_launch(void* const* d_in, const int* in_sizes, int n_in,
                              void* d_out, int out_size, void* d_ws, size_t ws_size,
                              hipStream_t stream) {
    const float* x    = (const float*)d_in[0];
    const float* Wih0 = (const float*)d_in[1];
    const float* Whh0 = (const float*)d_in[2];
    const float* b0   = (const float*)d_in[3];
    const float* Wih1 = (const float*)d_in[4];
    const float* Whh1 = (const float*)d_in[5];
    const float* b1   = (const float*)d_in[6];
    const float* Wfc  = (const float*)d_in[7];
    const float* bfc  = (const float*)d_in[8];
    float* out = (float*)d_out;

    auto need = [](int seg) -> size_t {
        return (size_t)2 * 16777216 * 2              // ysfrag hi+lo
             + (size_t)seg * 4096 * 64 * 4           // xpseg fp32
             + (size_t)seg * 32768 * 2 * 2           // xstage hi+lo
             + 262144 * 2                            // hfrag hi+lo
             + 262144                                // cT
             + 2048;                                 // ctr
    };
    int SEG = 8;
    if (ws_size < need(8)) SEG = 4;

    char* p = (char*)d_ws;
    _Float16* ysh = (_Float16*)p; p += (size_t)16777216 * 2;
    _Float16* ysl = (_Float16*)p; p += (size_t)16777216 * 2;
    float* xpseg  = (float*)p;    p += (size_t)SEG * 4096 * 64 * 4;
    _Float16* xsh = (_Float16*)p; p += (size_t)SEG * 32768 * 2;
    _Float16* xsl = (_Float16*)p; p += (size_t)SEG * 32768 * 2;
    _Float16* hfh = (_Float16*)p; p += 262144;
    _Float16* hfl = (_Float16*)p; p += 262144;
    float* cT     = (float*)p;    p += 262144;
    int* ctr      = (int*)p;

    const int ZN = (262144 * 3 + 2048) / 4;  // hfh|hfl|cT|ctr contiguous
    const int nseg = 256 / SEG;

    // ---- layer 0
    zero_kernel<<<(ZN + 255) / 256, 256, 0, stream>>>((float*)hfh, ZN);
    for (int s = 0; s < nseg; ++s) {
        int t0 = s * SEG;
        xT_kernel<<<SEG * 16, 256, 0, stream>>>(x, xsh, xsl, t0);
        xp_gemm<0><<<dim3(64, SEG / 4), 256, 0, stream>>>(Wih0, b0, xsh, xsl, xpseg, t0);
        rec_kernel<<<RECBLK, 256, 0, stream>>>(Whh0, xpseg, hfh, hfl, ysh, ysl, cT, ctr, t0, SEG, 0);
    }
    // ---- layer 1
    zero_kernel<<<(ZN + 255) / 256, 256, 0, stream>>>((float*)hfh, ZN);
    for (int s = 0; s < nseg; ++s) {
        int t0 = s * SEG;
        xp_gemm<1><<<dim3(64, SEG / 4), 256, 0, stream>>>(Wih1, b1, ysh, ysl, xpseg, t0);
        rec_kernel<<<RECBLK, 256, 0, stream>>>(Whh1, xpseg, hfh, hfl, nullptr, nullptr, cT, ctr, t0, SEG, 1);
    }
    fc_kernel<<<128, 256, 0, stream>>>(hfh, hfl, Wfc, bfc, out);
}

// Round 5
// 10515.363 us; speedup vs baseline: 2.8662x; 1.0923x over previous
//
#include <hip/hip_runtime.h>
#include <math.h>

#define BATCH 64
#define TT 256
#define IN_DIM 512
#define H 1024
#define RECBLK 256

typedef __attribute__((ext_vector_type(8))) _Float16 f16x8;
typedef __attribute__((ext_vector_type(4))) _Float16 f16x4;
typedef __attribute__((ext_vector_type(4))) float f32x4;

#define MFMA16 __builtin_amdgcn_mfma_f32_16x16x32_f16

__device__ __forceinline__ float sigm(float v) { return 1.f / (1.f + __expf(-v)); }
__device__ __forceinline__ float tanhf_(float v) {
    float e = __expf(-2.f * fabsf(v));
    float r = (1.f - e) / (1.f + e);
    return v < 0.f ? -r : r;
}
__device__ __forceinline__ void split16(float v, _Float16& hi, _Float16& lo) {
    hi = (_Float16)v;
    lo = (_Float16)((v - (float)hi) * 2048.0f);
}
// fragment index for value (j in [0,1024), b in [0,64)) within one 65536-elem timestep frag
__device__ __forceinline__ int fidx(int j, int b) {
    int c = j >> 5, kin = j & 31;
    int l = (b & 15) + ((kin >> 3) << 4);
    int n = b >> 4;
    return (((c * 4 + n) * 64) + l) * 8 + (kin & 7);
}

// ---------------------------------------------------------------------------
__global__ void zero_kernel(float* __restrict__ p, int n) {
    int i = blockIdx.x * 256 + threadIdx.x;
    if (i < n) p[i] = 0.f;
}

// ---------------------------------------------------------------------------
// transpose+split x[b][t][k] fp32 -> xstage frags, full sequence (4096 blocks)
__global__ __launch_bounds__(256) void xT_kernel(
    const float* __restrict__ x, _Float16* __restrict__ xh, _Float16* __restrict__ xl) {
    const int tid = threadIdx.x;
    const int n = tid >> 6, l = tid & 63;
    const int ti = blockIdx.x >> 4, c = blockIdx.x & 15;
    const int b = n * 16 + (l & 15);
    const int k = c * 32 + (l >> 4) * 8;
    const float* src = x + ((size_t)b * TT + ti) * IN_DIM + k;
    float4 v0 = *(const float4*)src;
    float4 v1 = *(const float4*)(src + 4);
    float tmp[8] = {v0.x, v0.y, v0.z, v0.w, v1.x, v1.y, v1.z, v1.w};
    f16x8 hi, lo;
#pragma unroll
    for (int e = 0; e < 8; ++e) { _Float16 h_, l_; split16(tmp[e], h_, l_); hi[e] = h_; lo[e] = l_; }
    size_t o = (((size_t)ti * 16 + c) * 4 + n) * 512 + l * 8;
    *(f16x8*)(xh + o) = hi;
    *(f16x8*)(xl + o) = lo;
}

// ---------------------------------------------------------------------------
// xp GEMM: xpseg[tiloc][rp][b] = sum_k W[rp][k]*B(t,b,k) + bias  (fp32 out)
// rp -> W row (rp&3)*H + (rp>>2). B from frag-layout f16 hi/lo arrays.
template<int LAYER>
__global__ __launch_bounds__(256, 1) void xp_gemm(
    const float* __restrict__ Wih, const float* __restrict__ bias,
    const _Float16* __restrict__ Bhi, const _Float16* __restrict__ Blo,
    float* __restrict__ xpseg, int t0) {
    const int K = LAYER ? 1024 : 512;
    __shared__ _Float16 AhiL[64 * 64];
    __shared__ _Float16 AloL[64 * 64];
    const int tid = threadIdx.x, l = tid & 63, w = tid >> 6;
    const int mbase = blockIdx.x * 64;
    const int tiloc = blockIdx.y * 4 + w;   // seg-local timestep
    const int arow = l & 15, akg = l >> 4;

    f32x4 ah[4][4], al[4][4];
#pragma unroll
    for (int m = 0; m < 4; ++m)
#pragma unroll
        for (int ns = 0; ns < 4; ++ns) { ah[m][ns] = (f32x4){0.f,0.f,0.f,0.f}; al[m][ns] = (f32x4){0.f,0.f,0.f,0.f}; }

    for (int kb = 0; kb < K / 64; ++kb) {
#pragma unroll
        for (int i = 0; i < 4; ++i) {
            int idx = tid + i * 256;
            int r = idx >> 4, kc = (idx & 15) * 4;
            int rp = mbase + r;
            const float* src = Wih + (size_t)((rp & 3) * H + (rp >> 2)) * K + kb * 64 + kc;
            float4 v = *(const float4*)src;
            int base = (r * 64 + kc) ^ ((r & 7) << 3);
            _Float16 h0, l0, h1, l1, h2, l2, h3, l3;
            split16(v.x, h0, l0); split16(v.y, h1, l1);
            split16(v.z, h2, l2); split16(v.w, h3, l3);
            *(f16x4*)&AhiL[base] = (f16x4){h0, h1, h2, h3};
            *(f16x4*)&AloL[base] = (f16x4){l0, l1, l2, l3};
        }
        __syncthreads();
#pragma unroll
        for (int c = 0; c < 2; ++c) {
            f16x8 Af[4], Afl[4];
#pragma unroll
            for (int m = 0; m < 4; ++m) {
                int row = m * 16 + arow;
                int ei = (row * 64 + c * 32 + akg * 8) ^ ((row & 7) << 3);
                Af[m] = *(const f16x8*)&AhiL[ei];
                Afl[m] = *(const f16x8*)&AloL[ei];
            }
            int cg = kb * 2 + c;
            int tglob = t0 + tiloc;
#pragma unroll
            for (int ns = 0; ns < 4; ++ns) {
                size_t boff;
                if (LAYER)
                    boff = (((size_t)tglob * 32 + cg) * 4 + ns) * 512 + l * 8;
                else
                    boff = (((size_t)tglob * 16 + cg) * 4 + ns) * 512 + l * 8;
                f16x8 bh = *(const f16x8*)(Bhi + boff);
                f16x8 bl = *(const f16x8*)(Blo + boff);
#pragma unroll
                for (int m = 0; m < 4; ++m) {
                    ah[m][ns] = MFMA16(Af[m], bh, ah[m][ns], 0, 0, 0);
                    al[m][ns] = MFMA16(Af[m], bl, al[m][ns], 0, 0, 0);
                    al[m][ns] = MFMA16(Afl[m], bh, al[m][ns], 0, 0, 0);
                }
            }
        }
        __syncthreads();
    }
#pragma unroll
    for (int m = 0; m < 4; ++m) {
#pragma unroll
        for (int r = 0; r < 4; ++r) {
            int rp = mbase + m * 16 + akg * 4 + r;
            float bv = bias[(rp & 3) * H + (rp >> 2)];
#pragma unroll
            for (int ns = 0; ns < 4; ++ns) {
                xpseg[((size_t)tiloc * 4096 + rp) * 64 + ns * 16 + arow] =
                    ah[m][ns][r] + al[m][ns][r] * (1.f / 2048.f) + bv;
            }
        }
    }
}

// ---------------------------------------------------------------------------
// Recurrence: 256 blocks x 512 thr, seg steps per launch. Block owns 16 gate
// rows (4 units). W frags in VGPRs (split f16), 8-way k-split across waves.
// Grid barrier: per-block flag store + parallel flag scan (no atomics).
__global__ __launch_bounds__(512, 2) void rec_kernel(
    const float* __restrict__ Whh, const float* __restrict__ xpseg,
    _Float16* __restrict__ hfh, _Float16* __restrict__ hfl,
    _Float16* __restrict__ ysh, _Float16* __restrict__ ysl,
    float* __restrict__ cT, int* __restrict__ flags, int t0, int seg, int layer) {
    __shared__ float scr[8][16][65];
    const int tid = threadIdx.x;
    const int bid = blockIdx.x;
    const int l = tid & 63;
    const int w = tid >> 6;           // 0..7
    const int arow = l & 15, akg = l >> 4;
    const int eb = tid & 63;

    // ---- W fragments: wave w owns k in [w*128, w*128+128) = 4 chunks of 32
    f16x8 Ah[4], Al[4];
    {
        const int rp = bid * 16 + arow;
        const float* src0 = Whh + (size_t)((rp & 3) * H + (rp >> 2)) * H;
#pragma unroll
        for (int c = 0; c < 4; ++c) {
            int k = w * 128 + c * 32 + akg * 8;
            float4 v0 = *(const float4*)(src0 + k);
            float4 v1 = *(const float4*)(src0 + k + 4);
            float tmp[8] = {v0.x, v0.y, v0.z, v0.w, v1.x, v1.y, v1.z, v1.w};
            f16x8 hi, lo;
#pragma unroll
            for (int e = 0; e < 8; ++e) { _Float16 h_, l_; split16(tmp[e], h_, l_); hi[e] = h_; lo[e] = l_; }
            Ah[c] = hi; Al[c] = lo;
        }
    }

    float cs = 0.f;
    if (tid < 256) cs = cT[(size_t)(bid * 4 + (tid >> 6)) * 64 + eb];

    for (int t = t0; t < t0 + seg; ++t) {
        const _Float16* bh = hfh + (size_t)(t & 1) * 65536;
        const _Float16* bl = hfl + (size_t)(t & 1) * 65536;

        // prefetch xp for this step (h-independent)
        float xpv[4];
        if (tid < 256) {
            const float* xb = xpseg + ((size_t)(t - t0) * 4096 + bid * 16 + (tid >> 6) * 4) * 64 + eb;
#pragma unroll
            for (int g = 0; g < 4; ++g) xpv[g] = xb[g * 64];
        }

        f32x4 ah[4], al2[4];
#pragma unroll
        for (int ns = 0; ns < 4; ++ns) { ah[ns] = (f32x4){0.f,0.f,0.f,0.f}; al2[ns] = (f32x4){0.f,0.f,0.f,0.f}; }

        f16x8 Bh[2][4], Bl[2][4];
        {
            int ch = w * 4;
#pragma unroll
            for (int ns = 0; ns < 4; ++ns) {
                Bh[0][ns] = *(const f16x8*)(bh + (size_t)(ch * 4 + ns) * 512 + l * 8);
                Bl[0][ns] = *(const f16x8*)(bl + (size_t)(ch * 4 + ns) * 512 + l * 8);
            }
        }
#pragma unroll
        for (int c = 0; c < 4; ++c) {
            const int cur = c & 1;
            if (c < 3) {
                int ch = w * 4 + c + 1;
#pragma unroll
                for (int ns = 0; ns < 4; ++ns) {
                    Bh[cur ^ 1][ns] = *(const f16x8*)(bh + (size_t)(ch * 4 + ns) * 512 + l * 8);
                    Bl[cur ^ 1][ns] = *(const f16x8*)(bl + (size_t)(ch * 4 + ns) * 512 + l * 8);
                }
            }
#pragma unroll
            for (int ns = 0; ns < 4; ++ns) {
                ah[ns]  = MFMA16(Ah[c], Bh[cur][ns], ah[ns], 0, 0, 0);
                al2[ns] = MFMA16(Ah[c], Bl[cur][ns], al2[ns], 0, 0, 0);
                al2[ns] = MFMA16(Al[c], Bh[cur][ns], al2[ns], 0, 0, 0);
            }
        }
        // ---- partial-K reduce via LDS
#pragma unroll
        for (int ns = 0; ns < 4; ++ns)
#pragma unroll
            for (int r = 0; r < 4; ++r)
                scr[w][akg * 4 + r][ns * 16 + arow] = ah[ns][r] + al2[ns][r] * (1.f / 2048.f);
        __syncthreads();

        if (tid < 256) {
            int eu = tid >> 6;
            float gg[4];
#pragma unroll
            for (int g = 0; g < 4; ++g) {
                int rl = eu * 4 + g;
                float s = 0.f;
#pragma unroll
                for (int ww = 0; ww < 8; ++ww) s += scr[ww][rl][eb];
                gg[g] = s + xpv[g];
            }
            float is = sigm(gg[0]), fs = sigm(gg[1]), gt = tanhf_(gg[2]), os = sigm(gg[3]);
            cs = fs * cs + is * gt;
            float hnew = os * tanhf_(cs);
            _Float16 hh, hl;
            split16(hnew, hh, hl);
            int j = bid * 4 + eu;
            int idx = fidx(j, eb);
            size_t so = (size_t)((t + 1) & 1) * 65536;
            hfh[so + idx] = hh; hfl[so + idx] = hl;
            if (layer == 0) { ysh[(size_t)t * 65536 + idx] = hh; ysl[(size_t)t * 65536 + idx] = hl; }
        }

        __syncthreads();   // drains h-store vmcnt; protects scr for next step
        if (t != t0 + seg - 1) {
            const int target = layer * TT + t + 1;
            if (w == 0) {
                if (l == 0) {
                    __builtin_amdgcn_fence(__ATOMIC_RELEASE, "agent");
                    __hip_atomic_store(&flags[bid], target, __ATOMIC_RELAXED, __HIP_MEMORY_SCOPE_AGENT);
                }
                bool done = false;
                while (!done) {
                    int m0 = __hip_atomic_load(&flags[l      ], __ATOMIC_RELAXED, __HIP_MEMORY_SCOPE_AGENT);
                    int m1 = __hip_atomic_load(&flags[l +  64], __ATOMIC_RELAXED, __HIP_MEMORY_SCOPE_AGENT);
                    int m2 = __hip_atomic_load(&flags[l + 128], __ATOMIC_RELAXED, __HIP_MEMORY_SCOPE_AGENT);
                    int m3 = __hip_atomic_load(&flags[l + 192], __ATOMIC_RELAXED, __HIP_MEMORY_SCOPE_AGENT);
                    int mn0 = m0 < m1 ? m0 : m1;
                    int mn1 = m2 < m3 ? m2 : m3;
                    int mn = mn0 < mn1 ? mn0 : mn1;
                    done = __all(mn >= target);
                    if (!done) __builtin_amdgcn_s_sleep(1);
                }
                __builtin_amdgcn_fence(__ATOMIC_ACQUIRE, "agent");
            }
            __syncthreads();
        }
    }
    if (tid < 256) cT[(size_t)(bid * 4 + (tid >> 6)) * 64 + eb] = cs;
}

// ---------------------------------------------------------------------------
__global__ __launch_bounds__(256) void fc_kernel(
    const _Float16* __restrict__ hh, const _Float16* __restrict__ hl,
    const float* __restrict__ Wfc, const float* __restrict__ bfc, float* __restrict__ out) {
    const int tid = threadIdx.x;
    const int b = tid & 63;
    const int o = blockIdx.x * 4 + (tid >> 6);
    const float* wr = Wfc + (size_t)o * H;
    float acc = 0.f;
    for (int jb = 0; jb < 128; ++jb) {
        int j = jb * 8;
        int idx = fidx(j, b);
        f16x8 vh = *(const f16x8*)(hh + idx);
        f16x8 vl = *(const f16x8*)(hl + idx);
#pragma unroll
        for (int e = 0; e < 8; ++e) {
            float hv = (float)vh[e] + (float)vl[e] * (1.f / 2048.f);
            acc += hv * wr[j + e];
        }
    }
    out[(size_t)b * 512 + o] = acc + bfc[o];
}

// ---------------------------------------------------------------------------
extern "C" void kernel_launch(void* const* d_in, const int* in_sizes, int n_in,
                              void* d_out, int out_size, void* d_ws, size_t ws_size,
                              hipStream_t stream) {
    const float* x    = (const float*)d_in[0];
    const float* Wih0 = (const float*)d_in[1];
    const float* Whh0 = (const float*)d_in[2];
    const float* b0   = (const float*)d_in[3];
    const float* Wih1 = (const float*)d_in[4];
    const float* Whh1 = (const float*)d_in[5];
    const float* b1   = (const float*)d_in[6];
    const float* Wfc  = (const float*)d_in[7];
    const float* bfc  = (const float*)d_in[8];
    float* out = (float*)d_out;

    // fixed buffers: ys hi/lo (67.1MB) + xs hi/lo (33.6MB) + tail (0.79MB)
    const size_t fixed_bytes = (size_t)67108864 + 33554432 + 787456;
    int SEG = 256;
    while (SEG > 4 && fixed_bytes + (size_t)SEG * 1048576 > ws_size) SEG >>= 1;

    char* p = (char*)d_ws;
    _Float16* ysh = (_Float16*)p; p += (size_t)16777216 * 2;
    _Float16* ysl = (_Float16*)p; p += (size_t)16777216 * 2;
    float* xpseg  = (float*)p;    p += (size_t)SEG * 1048576;
    _Float16* xsh = (_Float16*)p; p += (size_t)8388608 * 2;
    _Float16* xsl = (_Float16*)p; p += (size_t)8388608 * 2;
    _Float16* hfh = (_Float16*)p; p += 262144;
    _Float16* hfl = (_Float16*)p; p += 262144;
    float* cT     = (float*)p;    p += 262144;
    int* flags    = (int*)p;

    const int nseg = TT / SEG;

    xT_kernel<<<4096, 256, 0, stream>>>(x, xsh, xsl);

    for (int layer = 0; layer < 2; ++layer) {
        // zero hfh|hfl|cT (+flags on layer 0 only; flags sentinel is monotonic)
        int zn = layer == 0 ? 196864 : 196608;
        zero_kernel<<<(zn + 255) / 256, 256, 0, stream>>>((float*)hfh, zn);
        for (int s = 0; s < nseg; ++s) {
            int t0 = s * SEG;
            if (layer == 0)
                xp_gemm<0><<<dim3(64, SEG / 4), 256, 0, stream>>>(Wih0, b0, xsh, xsl, xpseg, t0);
            else
                xp_gemm<1><<<dim3(64, SEG / 4), 256, 0, stream>>>(Wih1, b1, ysh, ysl, xpseg, t0);
            rec_kernel<<<RECBLK, 512, 0, stream>>>(
                layer ? Whh1 : Whh0, xpseg, hfh, hfl, ysh, ysl, cT, flags, t0, SEG, layer);
        }
    }
    fc_kernel<<<128, 256, 0, stream>>>(hfh, hfl, Wfc, bfc, out);
}

// Round 6
// 8201.997 us; speedup vs baseline: 3.6746x; 1.2820x over previous
//
#include <hip/hip_runtime.h>
#include <math.h>

#define BATCH 64
#define TT 256
#define IN_DIM 512
#define H 1024
#define RECBLK 128

typedef __attribute__((ext_vector_type(8))) _Float16 f16x8;
typedef __attribute__((ext_vector_type(4))) _Float16 f16x4;
typedef __attribute__((ext_vector_type(4))) float f32x4;
typedef unsigned int u32;
typedef unsigned long long u64;

#define MFMA16 __builtin_amdgcn_mfma_f32_16x16x32_f16
#define SCOPE_AGENT __HIP_MEMORY_SCOPE_AGENT

union FB { u32 u[4]; f16x8 v; };

__device__ __forceinline__ float sigm(float v) { return 1.f / (1.f + __expf(-v)); }
__device__ __forceinline__ float tanhf_(float v) {
    float e = __expf(-2.f * fabsf(v));
    float r = (1.f - e) / (1.f + e);
    return v < 0.f ? -r : r;
}
__device__ __forceinline__ void split16(float v, _Float16& hi, _Float16& lo) {
    hi = (_Float16)v;
    lo = (_Float16)((v - (float)hi) * 2048.0f);
}
__device__ __forceinline__ u32 packu(float v) {
    _Float16 hi, lo; split16(v, hi, lo);
    return (u32)__builtin_bit_cast(unsigned short, hi)
         | ((u32)__builtin_bit_cast(unsigned short, lo) << 16);
}
// 4 u64 (8 packed vals, e=0..7) -> hi/lo f16x8 frags via v_perm
__device__ __forceinline__ void unpack8(const u64* r, f16x8& bh, f16x8& bl) {
    FB Hf, Lf;
#pragma unroll
    for (int i = 0; i < 4; ++i) {
        u32 p0 = (u32)r[i], p1 = (u32)(r[i] >> 32);
        Hf.u[i] = __builtin_amdgcn_perm(p1, p0, 0x05040100u);
        Lf.u[i] = __builtin_amdgcn_perm(p1, p0, 0x07060302u);
    }
    bh = Hf.v; bl = Lf.v;
}

// ---------------------------------------------------------------------------
__global__ void zero_kernel(u32* __restrict__ p, int n) {
    int i = blockIdx.x * 256 + threadIdx.x;
    if (i < n) p[i] = 0u;
}

// ---------------------------------------------------------------------------
// x[b][t][k] fp32 -> xpack[t][(k>>3)*512 + b*8 + (k&7)] packed u32
__global__ __launch_bounds__(512) void xT_kernel(
    const float* __restrict__ x, u32* __restrict__ xpack) {
    const int tid = threadIdx.x, t = blockIdx.x;
    const int b = tid & 63, kq = tid >> 6;
#pragma unroll
    for (int kb = 0; kb < 8; ++kb) {
        int k = kb * 64 + kq * 8;
        const float* src = x + ((size_t)b * TT + t) * IN_DIM + k;
        float4 v0 = *(const float4*)src;
        float4 v1 = *(const float4*)(src + 4);
        u32 o[8] = {packu(v0.x), packu(v0.y), packu(v0.z), packu(v0.w),
                    packu(v1.x), packu(v1.y), packu(v1.z), packu(v1.w)};
        u32* dst = xpack + (size_t)t * 32768 + (kb * 8 + kq) * 512 + b * 8;
        *(uint4*)dst = make_uint4(o[0], o[1], o[2], o[3]);
        *(uint4*)(dst + 4) = make_uint4(o[4], o[5], o[6], o[7]);
    }
}

// ---------------------------------------------------------------------------
// xp[tiloc][rp][b] = sum_k W[rp][k]*B(t,k,b) + bias. Block: 32 rows x 8 t.
// W row for rp: (rp&3)*H + (rp>>2). B from packed u32 (hi|lo<<16).
template<int LAYER>
__global__ __launch_bounds__(512, 2) void xp_gemm(
    const float* __restrict__ Wih, const float* __restrict__ bias,
    const u32* __restrict__ Bpack, float* __restrict__ xpseg, int t0) {
    const int K = LAYER ? 1024 : 512;
    const int TS = LAYER ? 65536 : 32768;     // u32 per timestep
    const int NKB = K / 64;
    __shared__ _Float16 AhiL[2][2048];
    __shared__ _Float16 AloL[2][2048];
    const int tid = threadIdx.x, l = tid & 63, w = tid >> 6;
    const int arow = l & 15, akg = l >> 4;
    const int mbase = blockIdx.x * 32;
    const int tiloc = blockIdx.y * 8 + w;
    const u32* bsrc = Bpack + (size_t)(t0 + tiloc) * TS;

    const int sr = tid >> 4, skc = (tid & 15) * 4;
    const int srp = mbase + sr;
    const float* wsrc = Wih + (size_t)((srp & 3) * H + (srp >> 2)) * K + skc;
    const int sbase = (sr * 64 + skc) ^ ((sr & 7) << 3);

    f32x4 ah[2][4], al[2][4];
#pragma unroll
    for (int m = 0; m < 2; ++m)
#pragma unroll
        for (int ns = 0; ns < 4; ++ns) { ah[m][ns] = (f32x4){0,0,0,0}; al[m][ns] = (f32x4){0,0,0,0}; }

    auto splitstore = [&](float4 v, int buf) {
        _Float16 h0,l0,h1,l1,h2,l2,h3,l3;
        split16(v.x,h0,l0); split16(v.y,h1,l1); split16(v.z,h2,l2); split16(v.w,h3,l3);
        *(f16x4*)&AhiL[buf][sbase] = (f16x4){h0,h1,h2,h3};
        *(f16x4*)&AloL[buf][sbase] = (f16x4){l0,l1,l2,l3};
    };

    float4 wpref = *(const float4*)wsrc;
    splitstore(wpref, 0);
    __syncthreads();

    for (int kb = 0; kb < NKB; ++kb) {
        if (kb + 1 < NKB) wpref = *(const float4*)(wsrc + (kb + 1) * 64);
#pragma unroll
        for (int c = 0; c < 2; ++c) {
            const int cg = kb * 2 + c;
            u64 raw[4][4];
#pragma unroll
            for (int ns = 0; ns < 4; ++ns) {
                const u64* bp = (const u64*)(bsrc + (size_t)(cg * 4 + akg) * 512 + (ns * 16 + arow) * 8);
#pragma unroll
                for (int i = 0; i < 4; ++i) raw[ns][i] = bp[i];
            }
            f16x8 Af[2], Afl[2];
#pragma unroll
            for (int m = 0; m < 2; ++m) {
                int row = m * 16 + arow;
                int ei = (row * 64 + c * 32 + akg * 8) ^ ((row & 7) << 3);
                Af[m] = *(const f16x8*)&AhiL[kb & 1][ei];
                Afl[m] = *(const f16x8*)&AloL[kb & 1][ei];
            }
#pragma unroll
            for (int ns = 0; ns < 4; ++ns) {
                f16x8 bh, bl;
                unpack8(raw[ns], bh, bl);
#pragma unroll
                for (int m = 0; m < 2; ++m) {
                    ah[m][ns] = MFMA16(Af[m], bh, ah[m][ns], 0, 0, 0);
                    al[m][ns] = MFMA16(Af[m], bl, al[m][ns], 0, 0, 0);
                    al[m][ns] = MFMA16(Afl[m], bh, al[m][ns], 0, 0, 0);
                }
            }
        }
        if (kb + 1 < NKB) splitstore(wpref, (kb + 1) & 1);
        __syncthreads();
    }
#pragma unroll
    for (int m = 0; m < 2; ++m)
#pragma unroll
        for (int r = 0; r < 4; ++r) {
            int rp = mbase + m * 16 + akg * 4 + r;
            float bv = bias[(rp & 3) * H + (rp >> 2)];
#pragma unroll
            for (int ns = 0; ns < 4; ++ns)
                xpseg[((size_t)tiloc * 4096 + rp) * 64 + ns * 16 + arow] =
                    ah[m][ns][r] + al[m][ns][r] * (1.f / 2048.f) + bv;
        }
}

// ---------------------------------------------------------------------------
// Recurrence: 128 blocks x 512 thr. Block owns 32 gate rows (8 units).
// W frags in VGPRs; h exchanged as packed u32 via agent-relaxed atomics (L3);
// flags barrier: release store + relaxed polls, no L2-invalidating fence.
__global__ __launch_bounds__(512, 2) void rec_kernel(
    const float* __restrict__ Whh, const float* __restrict__ xpseg,
    u32* hpack, u32* yspack, float* __restrict__ cT, int* flags,
    int t0, int seg, int layer) {
    __shared__ float scr[8][32][66];
    const int tid = threadIdx.x, bid = blockIdx.x;
    const int l = tid & 63, w = tid >> 6;
    const int arow = l & 15, akg = l >> 4;
    const int eb = l;

    // ---- A (W) fragments: wave w owns k in [w*128, w*128+128)
    f16x8 Ah[2][4], Al[2][4];
#pragma unroll
    for (int m = 0; m < 2; ++m) {
        const int rp = bid * 32 + m * 16 + arow;
        const float* src0 = Whh + (size_t)((rp & 3) * H + (rp >> 2)) * H;
#pragma unroll
        for (int c = 0; c < 4; ++c) {
            int k = w * 128 + c * 32 + akg * 8;
            float4 v0 = *(const float4*)(src0 + k);
            float4 v1 = *(const float4*)(src0 + k + 4);
            float tmp[8] = {v0.x, v0.y, v0.z, v0.w, v1.x, v1.y, v1.z, v1.w};
            f16x8 hi, lo;
#pragma unroll
            for (int e = 0; e < 8; ++e) { _Float16 h_, l_; split16(tmp[e], h_, l_); hi[e] = h_; lo[e] = l_; }
            Ah[m][c] = hi; Al[m][c] = lo;
        }
    }

    float cs = cT[(size_t)(bid * 8 + w) * 64 + eb];

    for (int t = t0; t < t0 + seg; ++t) {
        u32* hin = hpack + (size_t)(t & 1) * 65536;

        // xp prefetch (h-independent, issue first)
        float xpv[4];
        {
            const float* xb = xpseg + ((size_t)(t - t0) * 4096 + bid * 32 + w * 4) * 64 + eb;
#pragma unroll
            for (int g = 0; g < 4; ++g) xpv[g] = xb[g * 64];
        }

        f32x4 acch[2][4], accl[2][4];
#pragma unroll
        for (int m = 0; m < 2; ++m)
#pragma unroll
            for (int ns = 0; ns < 4; ++ns) { acch[m][ns] = (f32x4){0,0,0,0}; accl[m][ns] = (f32x4){0,0,0,0}; }

        u64 raw[2][4][4];
#pragma unroll
        for (int ns = 0; ns < 4; ++ns) {
            u64* bp = (u64*)(hin + (size_t)((w * 4 + 0) * 4 + akg) * 512 + (ns * 16 + arow) * 8);
#pragma unroll
            for (int i = 0; i < 4; ++i)
                raw[0][ns][i] = __hip_atomic_load(bp + i, __ATOMIC_RELAXED, SCOPE_AGENT);
        }
#pragma unroll
        for (int c = 0; c < 4; ++c) {
            const int cur = c & 1;
            if (c < 3) {
#pragma unroll
                for (int ns = 0; ns < 4; ++ns) {
                    u64* bp = (u64*)(hin + (size_t)((w * 4 + c + 1) * 4 + akg) * 512 + (ns * 16 + arow) * 8);
#pragma unroll
                    for (int i = 0; i < 4; ++i)
                        raw[cur ^ 1][ns][i] = __hip_atomic_load(bp + i, __ATOMIC_RELAXED, SCOPE_AGENT);
                }
            }
#pragma unroll
            for (int ns = 0; ns < 4; ++ns) {
                f16x8 bh, bl;
                unpack8(raw[cur][ns], bh, bl);
#pragma unroll
                for (int m = 0; m < 2; ++m) {
                    acch[m][ns] = MFMA16(Ah[m][c], bh, acch[m][ns], 0, 0, 0);
                    accl[m][ns] = MFMA16(Ah[m][c], bl, accl[m][ns], 0, 0, 0);
                    accl[m][ns] = MFMA16(Al[m][c], bh, accl[m][ns], 0, 0, 0);
                }
            }
        }
        // ---- partial-K reduce via LDS (stride 66 -> <=2-way conflicts)
#pragma unroll
        for (int m = 0; m < 2; ++m)
#pragma unroll
            for (int ns = 0; ns < 4; ++ns)
#pragma unroll
                for (int r = 0; r < 4; ++r)
                    scr[w][m * 16 + akg * 4 + r][ns * 16 + arow] =
                        acch[m][ns][r] + accl[m][ns][r] * (1.f / 2048.f);
        __syncthreads();

        // ---- epilogue: thread (unit=w, batch=eb)
        {
            float gg[4];
#pragma unroll
            for (int g = 0; g < 4; ++g) {
                int rl = w * 4 + g;
                float s = 0.f;
#pragma unroll
                for (int ww = 0; ww < 8; ++ww) s += scr[ww][rl][eb];
                gg[g] = s + xpv[g];
            }
            float is = sigm(gg[0]), fs = sigm(gg[1]), gt = tanhf_(gg[2]), os = sigm(gg[3]);
            cs = fs * cs + is * gt;
            float hnew = os * tanhf_(cs);
            u32 pk = packu(hnew);
            int sidx = bid * 512 + eb * 8 + w;
            __hip_atomic_store(&hpack[(size_t)((t + 1) & 1) * 65536 + sidx], pk,
                               __ATOMIC_RELAXED, SCOPE_AGENT);
            if (layer == 0)
                __hip_atomic_store(&yspack[(size_t)t * 65536 + sidx], pk,
                                   __ATOMIC_RELAXED, SCOPE_AGENT);
        }

        __syncthreads();   // all waves' stores drained (vmcnt) before flag
        if (t != t0 + seg - 1) {
            const int target = layer * TT + t + 1;
            if (w == 0) {
                if (l == 0)
                    __hip_atomic_store(&flags[bid], target, __ATOMIC_RELEASE, SCOPE_AGENT);
                bool done = false;
                while (!done) {
                    int m0 = __hip_atomic_load(&flags[l], __ATOMIC_RELAXED, SCOPE_AGENT);
                    int m1 = __hip_atomic_load(&flags[l + 64], __ATOMIC_RELAXED, SCOPE_AGENT);
                    int mn = m0 < m1 ? m0 : m1;
                    done = __all(mn >= target);
                    if (!done) __builtin_amdgcn_s_sleep(1);
                }
            }
            __builtin_amdgcn_sched_barrier(0);
            __syncthreads();
        }
    }
    cT[(size_t)(bid * 8 + w) * 64 + eb] = cs;
}

// ---------------------------------------------------------------------------
// out[b][o] = sum_j h[j][b] * Wfc[o][j] + bfc[o]; h from hpack slot 0
__global__ __launch_bounds__(256) void fc_kernel(
    const u32* __restrict__ hp, const float* __restrict__ Wfc,
    const float* __restrict__ bfc, float* __restrict__ out) {
    const int tid = threadIdx.x;
    const int b = tid & 63;
    const int o = blockIdx.x * 4 + (tid >> 6);
    const float* wr = Wfc + (size_t)o * H;
    float acc = 0.f;
    for (int jb = 0; jb < 128; ++jb) {
        const u64* bp = (const u64*)(hp + (size_t)jb * 512 + b * 8);
        u64 raw[4] = {bp[0], bp[1], bp[2], bp[3]};
        f16x8 vh, vl;
        unpack8(raw, vh, vl);
#pragma unroll
        for (int e = 0; e < 8; ++e) {
            float hv = (float)vh[e] + (float)vl[e] * (1.f / 2048.f);
            acc += hv * wr[jb * 8 + e];
        }
    }
    out[(size_t)b * 512 + o] = acc + bfc[o];
}

// ---------------------------------------------------------------------------
extern "C" void kernel_launch(void* const* d_in, const int* in_sizes, int n_in,
                              void* d_out, int out_size, void* d_ws, size_t ws_size,
                              hipStream_t stream) {
    const float* x    = (const float*)d_in[0];
    const float* Wih0 = (const float*)d_in[1];
    const float* Whh0 = (const float*)d_in[2];
    const float* b0   = (const float*)d_in[3];
    const float* Wih1 = (const float*)d_in[4];
    const float* Whh1 = (const float*)d_in[5];
    const float* b1   = (const float*)d_in[6];
    const float* Wfc  = (const float*)d_in[7];
    const float* bfc  = (const float*)d_in[8];
    float* out = (float*)d_out;

    // ys(67MB) + xpack(33.5MB) + xpseg(SEG MB) + hpack(512KB) + cT(256KB) + flags
    const size_t fixed_bytes = (size_t)67108864 + 33554432 + 524288 + 262144 + 512;
    int SEG = 256;
    while (SEG > 8 && fixed_bytes + (size_t)SEG * 1048576 > ws_size) SEG >>= 1;

    char* p = (char*)d_ws;
    u32* yspack  = (u32*)p;   p += (size_t)67108864;
    u32* xpack   = (u32*)p;   p += (size_t)33554432;
    float* xpseg = (float*)p; p += (size_t)SEG * 1048576;
    u32* hpack   = (u32*)p;   p += 524288;
    float* cT    = (float*)p; p += 262144;
    int* flags   = (int*)p;

    const int nseg = TT / SEG;

    xT_kernel<<<TT, 512, 0, stream>>>(x, xpack);

    for (int layer = 0; layer < 2; ++layer) {
        // zero hpack|cT (+flags once; flag sentinel is monotonic across layers)
        int zn = (layer == 0) ? 196736 : 196608;
        zero_kernel<<<(zn + 255) / 256, 256, 0, stream>>>((u32*)hpack, zn);
        for (int s = 0; s < nseg; ++s) {
            int t0 = s * SEG;
            if (layer == 0)
                xp_gemm<0><<<dim3(128, SEG / 8), 512, 0, stream>>>(Wih0, b0, xpack, xpseg, t0);
            else
                xp_gemm<1><<<dim3(128, SEG / 8), 512, 0, stream>>>(Wih1, b1, yspack, xpseg, t0);
            rec_kernel<<<RECBLK, 512, 0, stream>>>(
                layer ? Whh1 : Whh0, xpseg, hpack, yspack, cT, flags, t0, SEG, layer);
        }
    }
    fc_kernel<<<128, 256, 0, stream>>>(hpack, Wfc, bfc, out);
}

// Round 7
// 7116.427 us; speedup vs baseline: 4.2351x; 1.1525x over previous
//
#include <hip/hip_runtime.h>
#include <math.h>

#define BATCH 64
#define TT 256
#define IN_DIM 512
#define H 1024
#define RECBLK 128
#define SLOT 65536   // u32 per h slot (1024 j x 64 b)
#define XSLOT 32768  // u32 per x slot

typedef __attribute__((ext_vector_type(8))) _Float16 f16x8;
typedef __attribute__((ext_vector_type(4))) float f32x4;
typedef unsigned int u32;
typedef unsigned long long u64;

#define MFMA16 __builtin_amdgcn_mfma_f32_16x16x32_f16
#define SCOPE_AGENT __HIP_MEMORY_SCOPE_AGENT

union FB { u32 u[4]; f16x8 v; };

__device__ __forceinline__ float sigm(float v) { return 1.f / (1.f + __expf(-v)); }
__device__ __forceinline__ float tanhf_(float v) {
    float e = __expf(-2.f * fabsf(v));
    float r = (1.f - e) / (1.f + e);
    return v < 0.f ? -r : r;
}
__device__ __forceinline__ void split16(float v, _Float16& hi, _Float16& lo) {
    hi = (_Float16)v;
    lo = (_Float16)((v - (float)hi) * 2048.0f);
}
__device__ __forceinline__ u32 packu(float v) {
    _Float16 hi, lo; split16(v, hi, lo);
    return (u32)__builtin_bit_cast(unsigned short, hi)
         | ((u32)__builtin_bit_cast(unsigned short, lo) << 16);
}
__device__ __forceinline__ void unpack8(const u64* r, f16x8& bh, f16x8& bl) {
    FB Hf, Lf;
#pragma unroll
    for (int i = 0; i < 4; ++i) {
        u32 p0 = (u32)r[i], p1 = (u32)(r[i] >> 32);
        Hf.u[i] = __builtin_amdgcn_perm(p1, p0, 0x05040100u);
        Lf.u[i] = __builtin_amdgcn_perm(p1, p0, 0x07060302u);
    }
    bh = Hf.v; bl = Lf.v;
}

// ---------------------------------------------------------------------------
__global__ void zero_kernel(u32* __restrict__ p, int n) {
    int i = blockIdx.x * 256 + threadIdx.x;
    if (i < n) p[i] = 0u;
}

// ---------------------------------------------------------------------------
// W fp32 -> Wsplit packed u32, row-permuted: Wsplit[rp][k] = pack(W[(rp&3)*H + (rp>>2)][k])
__global__ __launch_bounds__(256) void wprep_kernel(
    const float* __restrict__ Wih0, const float* __restrict__ Whh0,
    const float* __restrict__ Wih1, const float* __restrict__ Whh1,
    u32* __restrict__ wsp) {
    const int m = blockIdx.y, rp = blockIdx.x, tid = threadIdx.x;
    const float* W; u32* dst; int K;
    if (m == 0)      { W = Wih0; K = 512;  dst = wsp; }
    else if (m == 1) { W = Whh0; K = 1024; dst = wsp + 2097152; }
    else if (m == 2) { W = Wih1; K = 1024; dst = wsp + 6291456; }
    else             { W = Whh1; K = 1024; dst = wsp + 10485760; }
    int k = tid * 4;
    if (k < K) {
        const float* src = W + (size_t)((rp & 3) * H + (rp >> 2)) * K + k;
        float4 v = *(const float4*)src;
        uint4 o = make_uint4(packu(v.x), packu(v.y), packu(v.z), packu(v.w));
        *(uint4*)(dst + (size_t)rp * K + k) = o;
    }
}

// ---------------------------------------------------------------------------
// x[b][t][k] fp32 -> xpack[t][(k>>3)*512 + b*8 + (k&7)] packed u32
__global__ __launch_bounds__(512) void xT_kernel(
    const float* __restrict__ x, u32* __restrict__ xpack) {
    const int tid = threadIdx.x, t = blockIdx.x;
    const int b = tid & 63, kq = tid >> 6;
#pragma unroll
    for (int kb = 0; kb < 8; ++kb) {
        int k = kb * 64 + kq * 8;
        const float* src = x + ((size_t)b * TT + t) * IN_DIM + k;
        float4 v0 = *(const float4*)src;
        float4 v1 = *(const float4*)(src + 4);
        u32 o[8] = {packu(v0.x), packu(v0.y), packu(v0.z), packu(v0.w),
                    packu(v1.x), packu(v1.y), packu(v1.z), packu(v1.w)};
        u32* dst = xpack + (size_t)t * XSLOT + (kb * 8 + kq) * 512 + b * 8;
        *(uint4*)dst = make_uint4(o[0], o[1], o[2], o[3]);
        *(uint4*)(dst + 4) = make_uint4(o[4], o[5], o[6], o[7]);
    }
}

// ---------------------------------------------------------------------------
// xp GEMM v3: Mtile=256 (8 m-waves), 4 timesteps/block, B LDS-staged per kb.
// LAYER 0: B = xpack slot t; LAYER 1: B = ys slot t+1.
template<int LAYER>
__global__ __launch_bounds__(512, 2) void xp_gemm(
    const u32* __restrict__ Wsp, const float* __restrict__ bias,
    const u32* __restrict__ Bpack, float* __restrict__ xpseg, int t0) {
    const int K = LAYER ? 1024 : 512;
    const int NKB = K / 64;
    const int TS = LAYER ? SLOT : XSLOT;
    __shared__ u32 Bl[2][4096];
    const int tid = threadIdx.x, l = tid & 63, w = tid >> 6;
    const int arow = l & 15, akg = l >> 4;
    const int mbase = blockIdx.x * 256;
    const int rp0 = mbase + w * 32 + arow;
    const u32* wr0p = Wsp + (size_t)rp0 * K;
    const u32* wr1p = Wsp + (size_t)(rp0 + 16) * K;

    for (int tl = 0; tl < 4; ++tl) {
        const int t = t0 + blockIdx.y * 4 + tl;
        const u32* bsrc = Bpack + (size_t)(t + LAYER) * TS;

        f32x4 ah[2][4], al[2][4];
#pragma unroll
        for (int m = 0; m < 2; ++m)
#pragma unroll
            for (int ns = 0; ns < 4; ++ns) { ah[m][ns] = (f32x4){0,0,0,0}; al[m][ns] = (f32x4){0,0,0,0}; }

        {
            uint4 a = *(const uint4*)(bsrc + tid * 8);
            uint4 b = *(const uint4*)(bsrc + tid * 8 + 4);
            *(uint4*)&Bl[0][tid * 8] = a;
            *(uint4*)&Bl[0][tid * 8 + 4] = b;
        }
        __syncthreads();

        for (int kb = 0; kb < NKB; ++kb) {
            const int cur = kb & 1;
            if (kb + 1 < NKB) {
                uint4 a = *(const uint4*)(bsrc + (size_t)(kb + 1) * 4096 + tid * 8);
                uint4 b = *(const uint4*)(bsrc + (size_t)(kb + 1) * 4096 + tid * 8 + 4);
                *(uint4*)&Bl[cur ^ 1][tid * 8] = a;
                *(uint4*)&Bl[cur ^ 1][tid * 8 + 4] = b;
            }
#pragma unroll
            for (int cgl = 0; cgl < 2; ++cgl) {
                const int kk = kb * 64 + cgl * 32 + akg * 8;
                u64 wraw0[4], wraw1[4];
                *(uint4*)&wraw0[0] = *(const uint4*)(wr0p + kk);
                *(uint4*)&wraw0[2] = *(const uint4*)(wr0p + kk + 4);
                *(uint4*)&wraw1[0] = *(const uint4*)(wr1p + kk);
                *(uint4*)&wraw1[2] = *(const uint4*)(wr1p + kk + 4);
                f16x8 Wh0, Wl0, Wh1, Wl1;
                unpack8(wraw0, Wh0, Wl0);
                unpack8(wraw1, Wh1, Wl1);
#pragma unroll
                for (int ns = 0; ns < 4; ++ns) {
                    const u32* bp = &Bl[cur][(cgl * 4 + akg) * 512 + (ns * 16 + arow) * 8];
                    u64 br[4];
                    *(uint4*)&br[0] = *(const uint4*)bp;
                    *(uint4*)&br[2] = *(const uint4*)(bp + 4);
                    f16x8 bh, bl_;
                    unpack8(br, bh, bl_);
                    ah[0][ns] = MFMA16(Wh0, bh, ah[0][ns], 0, 0, 0);
                    al[0][ns] = MFMA16(Wh0, bl_, al[0][ns], 0, 0, 0);
                    al[0][ns] = MFMA16(Wl0, bh, al[0][ns], 0, 0, 0);
                    ah[1][ns] = MFMA16(Wh1, bh, ah[1][ns], 0, 0, 0);
                    al[1][ns] = MFMA16(Wh1, bl_, al[1][ns], 0, 0, 0);
                    al[1][ns] = MFMA16(Wl1, bh, al[1][ns], 0, 0, 0);
                }
            }
            __syncthreads();
        }
        // epilogue: D row = m*16 + akg*4 + r, col = ns*16 + arow
#pragma unroll
        for (int m = 0; m < 2; ++m)
#pragma unroll
            for (int r = 0; r < 4; ++r) {
                int rp = mbase + w * 32 + m * 16 + akg * 4 + r;
                float bv = bias[(rp & 3) * H + (rp >> 2)];
#pragma unroll
                for (int ns = 0; ns < 4; ++ns)
                    xpseg[((size_t)(t - t0) * 4096 + rp) * 64 + ns * 16 + arow] =
                        ah[m][ns][r] + al[m][ns][r] * (1.f / 2048.f) + bv;
            }
        if (tl < 3) __syncthreads();
    }
}

// ---------------------------------------------------------------------------
// Recurrence: 128 blocks x 512 thr. Block owns 32 gate rows (8 units).
// h slots t-indexed in hbuf (slot 0 = zeros, slot t+1 = h_t): consumers use
// NORMAL L2-cached loads (each slot written once, before its flag); producers
// do dense relaxed-atomic u32 stores (writethrough to L3) after LDS transpose.
__global__ __launch_bounds__(512, 1) void rec_kernel(
    const u32* __restrict__ WspHH, const float* __restrict__ xpseg,
    u32* hbuf, float* __restrict__ cT, int* flags, int t0, int seg, int layer) {
    __shared__ float scr[8][32][66];
    __shared__ u32 hx[8 * 72];
    const int tid = threadIdx.x, bid = blockIdx.x;
    const int l = tid & 63, w = tid >> 6;
    const int arow = l & 15, akg = l >> 4;
    const int eb = l;

    // ---- A (W_hh) fragments from packed Wsplit: wave w owns k in [w*128, +128)
    f16x8 Ah[2][4], Al[2][4];
#pragma unroll
    for (int m = 0; m < 2; ++m) {
        const int rp = bid * 32 + m * 16 + arow;
        const u32* wrow = WspHH + (size_t)rp * 1024;
#pragma unroll
        for (int c = 0; c < 4; ++c) {
            int kk = w * 128 + c * 32 + akg * 8;
            u64 r[4];
            *(uint4*)&r[0] = *(const uint4*)(wrow + kk);
            *(uint4*)&r[2] = *(const uint4*)(wrow + kk + 4);
            unpack8(r, Ah[m][c], Al[m][c]);
        }
    }

    float cs = (t0 > 0) ? cT[(size_t)(bid * 8 + w) * 64 + eb] : 0.f;

    for (int t = t0; t < t0 + seg; ++t) {
        const u32* hin = hbuf + (size_t)t * SLOT;

        float xpv[4];
        {
            const float* xb = xpseg + ((size_t)(t - t0) * 4096 + bid * 32 + w * 4) * 64 + eb;
#pragma unroll
            for (int g = 0; g < 4; ++g) xpv[g] = xb[g * 64];
        }

        f32x4 acch[2][4], accl[2][4];
#pragma unroll
        for (int m = 0; m < 2; ++m)
#pragma unroll
            for (int ns = 0; ns < 4; ++ns) { acch[m][ns] = (f32x4){0,0,0,0}; accl[m][ns] = (f32x4){0,0,0,0}; }

        u64 raw[2][4][4];
#pragma unroll
        for (int ns = 0; ns < 4; ++ns) {
            const u32* bp = hin + (size_t)((w * 4 + 0) * 4 + akg) * 512 + (ns * 16 + arow) * 8;
            *(uint4*)&raw[0][ns][0] = *(const uint4*)bp;
            *(uint4*)&raw[0][ns][2] = *(const uint4*)(bp + 4);
        }
#pragma unroll
        for (int c = 0; c < 4; ++c) {
            const int cur = c & 1;
            if (c < 3) {
#pragma unroll
                for (int ns = 0; ns < 4; ++ns) {
                    const u32* bp = hin + (size_t)((w * 4 + c + 1) * 4 + akg) * 512 + (ns * 16 + arow) * 8;
                    *(uint4*)&raw[cur ^ 1][ns][0] = *(const uint4*)bp;
                    *(uint4*)&raw[cur ^ 1][ns][2] = *(const uint4*)(bp + 4);
                }
            }
#pragma unroll
            for (int ns = 0; ns < 4; ++ns) {
                f16x8 bh, bl;
                unpack8(raw[cur][ns], bh, bl);
#pragma unroll
                for (int m = 0; m < 2; ++m) {
                    acch[m][ns] = MFMA16(Ah[m][c], bh, acch[m][ns], 0, 0, 0);
                    accl[m][ns] = MFMA16(Ah[m][c], bl, accl[m][ns], 0, 0, 0);
                    accl[m][ns] = MFMA16(Al[m][c], bh, accl[m][ns], 0, 0, 0);
                }
            }
        }
        // ---- partial-K reduce via LDS
#pragma unroll
        for (int m = 0; m < 2; ++m)
#pragma unroll
            for (int ns = 0; ns < 4; ++ns)
#pragma unroll
                for (int r = 0; r < 4; ++r)
                    scr[w][m * 16 + akg * 4 + r][ns * 16 + arow] =
                        acch[m][ns][r] + accl[m][ns][r] * (1.f / 2048.f);
        __syncthreads();

        // ---- epilogue: thread (unit=w, batch=eb)
        {
            float gg[4];
#pragma unroll
            for (int g = 0; g < 4; ++g) {
                int rl = w * 4 + g;
                float s = 0.f;
#pragma unroll
                for (int ww = 0; ww < 8; ++ww) s += scr[ww][rl][eb];
                gg[g] = s + xpv[g];
            }
            float is = sigm(gg[0]), fs = sigm(gg[1]), gt = tanhf_(gg[2]), os = sigm(gg[3]);
            cs = fs * cs + is * gt;
            float hnew = os * tanhf_(cs);
            hx[w * 72 + eb] = packu(hnew);
        }
        __syncthreads();

        // ---- dense store: block's 512 values -> contiguous 2KB at slot t+1
        {
            u32 pko = hx[(tid & 7) * 72 + (tid >> 3)];
            __hip_atomic_store(&hbuf[(size_t)(t + 1) * SLOT + bid * 512 + tid], pko,
                               __ATOMIC_RELAXED, SCOPE_AGENT);
        }
        __syncthreads();   // all waves' stores vmcnt-drained before flag

        if (t != t0 + seg - 1) {
            const int target = layer * TT + t + 1;
            if (w == 0) {
                if (l == 0)
                    __hip_atomic_store(&flags[bid], target, __ATOMIC_RELEASE, SCOPE_AGENT);
                bool done = false;
                while (!done) {
                    int m0 = __hip_atomic_load(&flags[l], __ATOMIC_RELAXED, SCOPE_AGENT);
                    int m1 = __hip_atomic_load(&flags[l + 64], __ATOMIC_RELAXED, SCOPE_AGENT);
                    int mn = m0 < m1 ? m0 : m1;
                    done = __all(mn >= target);
                    if (!done) __builtin_amdgcn_s_sleep(1);
                }
            }
            __builtin_amdgcn_sched_barrier(0);
            __syncthreads();
        }
    }
    cT[(size_t)(bid * 8 + w) * 64 + eb] = cs;
}

// ---------------------------------------------------------------------------
// out[b][o] = sum_j h[j][b] * Wfc[o][j] + bfc[o]; h from hs1 slot 256
__global__ __launch_bounds__(256) void fc_kernel(
    const u32* __restrict__ hp, const float* __restrict__ Wfc,
    const float* __restrict__ bfc, float* __restrict__ out) {
    const int tid = threadIdx.x;
    const int b = tid & 63;
    const int o = blockIdx.x * 4 + (tid >> 6);
    const float* wr = Wfc + (size_t)o * H;
    float acc = 0.f;
    for (int jb = 0; jb < 128; ++jb) {
        const u64* bp = (const u64*)(hp + (size_t)jb * 512 + b * 8);
        u64 raw[4] = {bp[0], bp[1], bp[2], bp[3]};
        f16x8 vh, vl;
        unpack8(raw, vh, vl);
#pragma unroll
        for (int e = 0; e < 8; ++e) {
            float hv = (float)vh[e] + (float)vl[e] * (1.f / 2048.f);
            acc += hv * wr[jb * 8 + e];
        }
    }
    out[(size_t)b * 512 + o] = acc + bfc[o];
}

// ---------------------------------------------------------------------------
extern "C" void kernel_launch(void* const* d_in, const int* in_sizes, int n_in,
                              void* d_out, int out_size, void* d_ws, size_t ws_size,
                              hipStream_t stream) {
    const float* x    = (const float*)d_in[0];
    const float* Wih0 = (const float*)d_in[1];
    const float* Whh0 = (const float*)d_in[2];
    const float* b0   = (const float*)d_in[3];
    const float* Wih1 = (const float*)d_in[4];
    const float* Whh1 = (const float*)d_in[5];
    const float* b1   = (const float*)d_in[6];
    const float* Wfc  = (const float*)d_in[7];
    const float* bfc  = (const float*)d_in[8];
    float* out = (float*)d_out;

    // fixed u32: ys 257*SLOT + hs1 257*SLOT + xpack 256*XSLOT + Wsplit + cT + flags
    const size_t fixed_bytes =
        ((size_t)257 * SLOT * 2 + (size_t)256 * XSLOT + 14680064 + 65536 + 128) * 4;
    int SEG = 256;
    while (SEG > 8 && fixed_bytes + (size_t)SEG * 1048576 > ws_size) SEG >>= 1;

    char* p = (char*)d_ws;
    u32* ys     = (u32*)p;   p += (size_t)257 * SLOT * 4;
    u32* hs1    = (u32*)p;   p += (size_t)257 * SLOT * 4;
    u32* xpack  = (u32*)p;   p += (size_t)256 * XSLOT * 4;
    u32* wsplit = (u32*)p;   p += (size_t)14680064 * 4;
    float* xpseg = (float*)p; p += (size_t)SEG * 1048576;
    float* cT   = (float*)p; p += 262144;
    int* flags  = (int*)p;

    const u32* whh0s = wsplit + 2097152;
    const u32* wih1s = wsplit + 6291456;
    const u32* whh1s = wsplit + 10485760;

    // zero slot-0 of ys/hs1 + flags (every launch: flags must restart at 0)
    zero_kernel<<<SLOT / 256, 256, 0, stream>>>(ys, SLOT);
    zero_kernel<<<SLOT / 256, 256, 0, stream>>>(hs1, SLOT);
    zero_kernel<<<1, 256, 0, stream>>>((u32*)flags, 128);

    wprep_kernel<<<dim3(4096, 4), 256, 0, stream>>>(Wih0, Whh0, Wih1, Whh1, wsplit);
    xT_kernel<<<TT, 512, 0, stream>>>(x, xpack);

    const int nseg = TT / SEG;
    for (int layer = 0; layer < 2; ++layer) {
        for (int s = 0; s < nseg; ++s) {
            int t0 = s * SEG;
            if (layer == 0)
                xp_gemm<0><<<dim3(16, SEG / 4), 512, 0, stream>>>(wsplit, b0, xpack, xpseg, t0);
            else
                xp_gemm<1><<<dim3(16, SEG / 4), 512, 0, stream>>>(wih1s, b1, ys, xpseg, t0);
            rec_kernel<<<RECBLK, 512, 0, stream>>>(
                layer ? whh1s : whh0s, xpseg, layer ? hs1 : ys, cT, flags, t0, SEG, layer);
        }
    }
    fc_kernel<<<128, 256, 0, stream>>>(hs1 + (size_t)256 * SLOT, Wfc, bfc, out);
}

// Round 8
// 5918.636 us; speedup vs baseline: 5.0922x; 1.2024x over previous
//
#include <hip/hip_runtime.h>
#include <math.h>

#define BATCH 64
#define TT 256
#define IN_DIM 512
#define H 1024
#define RECBLK 128
#define SLOT 65536   // u32 per h slot (1024 j x 64 b)
#define XSLOT 32768  // u32 per x slot

typedef __attribute__((ext_vector_type(8))) _Float16 f16x8;
typedef __attribute__((ext_vector_type(4))) float f32x4;
typedef unsigned int u32;
typedef unsigned long long u64;

#define MFMA16 __builtin_amdgcn_mfma_f32_16x16x32_f16
#define SCOPE_AGENT __HIP_MEMORY_SCOPE_AGENT

union FB { u32 u[4]; f16x8 v; };

__device__ __forceinline__ float sigm(float v) { return 1.f / (1.f + __expf(-v)); }
__device__ __forceinline__ float tanhf_(float v) {
    float e = __expf(-2.f * fabsf(v));
    float r = (1.f - e) / (1.f + e);
    return v < 0.f ? -r : r;
}
__device__ __forceinline__ void split16(float v, _Float16& hi, _Float16& lo) {
    hi = (_Float16)v;
    lo = (_Float16)((v - (float)hi) * 2048.0f);
}
__device__ __forceinline__ u32 packu(float v) {
    _Float16 hi, lo; split16(v, hi, lo);
    return (u32)__builtin_bit_cast(unsigned short, hi)
         | ((u32)__builtin_bit_cast(unsigned short, lo) << 16);
}
__device__ __forceinline__ void unpack8(const u64* r, f16x8& bh, f16x8& bl) {
    FB Hf, Lf;
#pragma unroll
    for (int i = 0; i < 4; ++i) {
        u32 p0 = (u32)r[i], p1 = (u32)(r[i] >> 32);
        Hf.u[i] = __builtin_amdgcn_perm(p1, p0, 0x05040100u);
        Lf.u[i] = __builtin_amdgcn_perm(p1, p0, 0x07060302u);
    }
    bh = Hf.v; bl = Lf.v;
}
__device__ __forceinline__ void split8(const float4& a0, const float4& a1, f16x8& hi, f16x8& lo) {
    float tmp[8] = {a0.x, a0.y, a0.z, a0.w, a1.x, a1.y, a1.z, a1.w};
#pragma unroll
    for (int e = 0; e < 8; ++e) { _Float16 h_, l_; split16(tmp[e], h_, l_); hi[e] = h_; lo[e] = l_; }
}

// ---------------------------------------------------------------------------
__global__ void zero_kernel(u32* __restrict__ p, int n) {
    int i = blockIdx.x * 256 + threadIdx.x;
    if (i < n) p[i] = 0u;
}

// ---------------------------------------------------------------------------
// x[b][t][k] fp32 -> xpack[t][(k>>3)*512 + b*8 + (k&7)] packed u32
__global__ __launch_bounds__(512) void xT_kernel(
    const float* __restrict__ x, u32* __restrict__ xpack) {
    const int tid = threadIdx.x, t = blockIdx.x;
    const int b = tid & 63, kq = tid >> 6;
#pragma unroll
    for (int kb = 0; kb < 8; ++kb) {
        int k = kb * 64 + kq * 8;
        const float* src = x + ((size_t)b * TT + t) * IN_DIM + k;
        float4 v0 = *(const float4*)src;
        float4 v1 = *(const float4*)(src + 4);
        u32 o[8] = {packu(v0.x), packu(v0.y), packu(v0.z), packu(v0.w),
                    packu(v1.x), packu(v1.y), packu(v1.z), packu(v1.w)};
        u32* dst = xpack + (size_t)t * XSLOT + (kb * 8 + kq) * 512 + b * 8;
        *(uint4*)dst = make_uint4(o[0], o[1], o[2], o[3]);
        *(uint4*)(dst + 4) = make_uint4(o[4], o[5], o[6], o[7]);
    }
}

// ---------------------------------------------------------------------------
// xp GEMM: Mtile=256 (8 m-waves share LDS-staged B), 4 timesteps/block.
// W fp32, split inline to hi/lo f16 fragments (row permute rp->(rp&3)*H+(rp>>2)).
// LAYER 0: B = xpack slot t; LAYER 1: B = ys slot t+1.
template<int LAYER>
__global__ __launch_bounds__(512, 2) void xp_gemm(
    const float* __restrict__ Wih, const float* __restrict__ bias,
    const u32* __restrict__ Bpack, float* __restrict__ xpseg, int t0) {
    const int K = LAYER ? 1024 : 512;
    const int NKB = K / 64;
    const int TS = LAYER ? SLOT : XSLOT;
    __shared__ u32 Bl[2][4096];
    const int tid = threadIdx.x, l = tid & 63, w = tid >> 6;
    const int arow = l & 15, akg = l >> 4;
    const int mbase = blockIdx.x * 256;
    const int rp0 = mbase + w * 32 + arow;
    const float* wr0p = Wih + (size_t)((rp0 & 3) * H + (rp0 >> 2)) * K;
    const float* wr1p = wr0p + (size_t)4 * K;   // row for rp0+16

    for (int tl = 0; tl < 4; ++tl) {
        const int t = t0 + blockIdx.y * 4 + tl;
        const u32* bsrc = Bpack + (size_t)(t + LAYER) * TS;

        f32x4 ah[2][4], al[2][4];
#pragma unroll
        for (int m = 0; m < 2; ++m)
#pragma unroll
            for (int ns = 0; ns < 4; ++ns) { ah[m][ns] = (f32x4){0,0,0,0}; al[m][ns] = (f32x4){0,0,0,0}; }

        {
            uint4 a = *(const uint4*)(bsrc + tid * 8);
            uint4 b = *(const uint4*)(bsrc + tid * 8 + 4);
            *(uint4*)&Bl[0][tid * 8] = a;
            *(uint4*)&Bl[0][tid * 8 + 4] = b;
        }
        __syncthreads();

        for (int kb = 0; kb < NKB; ++kb) {
            const int cur = kb & 1;
            if (kb + 1 < NKB) {
                uint4 a = *(const uint4*)(bsrc + (size_t)(kb + 1) * 4096 + tid * 8);
                uint4 b = *(const uint4*)(bsrc + (size_t)(kb + 1) * 4096 + tid * 8 + 4);
                *(uint4*)&Bl[cur ^ 1][tid * 8] = a;
                *(uint4*)&Bl[cur ^ 1][tid * 8 + 4] = b;
            }
#pragma unroll
            for (int cgl = 0; cgl < 2; ++cgl) {
                const int kk = kb * 64 + cgl * 32 + akg * 8;
                float4 a0 = *(const float4*)(wr0p + kk);
                float4 a1 = *(const float4*)(wr0p + kk + 4);
                float4 c0 = *(const float4*)(wr1p + kk);
                float4 c1 = *(const float4*)(wr1p + kk + 4);
                f16x8 Wh0, Wl0, Wh1, Wl1;
                split8(a0, a1, Wh0, Wl0);
                split8(c0, c1, Wh1, Wl1);
#pragma unroll
                for (int ns = 0; ns < 4; ++ns) {
                    const u32* bp = &Bl[cur][(cgl * 4 + akg) * 512 + (ns * 16 + arow) * 8];
                    u64 br[4];
                    *(uint4*)&br[0] = *(const uint4*)bp;
                    *(uint4*)&br[2] = *(const uint4*)(bp + 4);
                    f16x8 bh, bl_;
                    unpack8(br, bh, bl_);
                    ah[0][ns] = MFMA16(Wh0, bh, ah[0][ns], 0, 0, 0);
                    al[0][ns] = MFMA16(Wh0, bl_, al[0][ns], 0, 0, 0);
                    al[0][ns] = MFMA16(Wl0, bh, al[0][ns], 0, 0, 0);
                    ah[1][ns] = MFMA16(Wh1, bh, ah[1][ns], 0, 0, 0);
                    al[1][ns] = MFMA16(Wh1, bl_, al[1][ns], 0, 0, 0);
                    al[1][ns] = MFMA16(Wl1, bh, al[1][ns], 0, 0, 0);
                }
            }
            __syncthreads();
        }
        // epilogue: D row = m*16 + akg*4 + r, col = ns*16 + arow
#pragma unroll
        for (int m = 0; m < 2; ++m)
#pragma unroll
            for (int r = 0; r < 4; ++r) {
                int rp = mbase + w * 32 + m * 16 + akg * 4 + r;
                float bv = bias[(rp & 3) * H + (rp >> 2)];
#pragma unroll
                for (int ns = 0; ns < 4; ++ns)
                    xpseg[((size_t)(t - t0) * 4096 + rp) * 64 + ns * 16 + arow] =
                        ah[m][ns][r] + al[m][ns][r] * (1.f / 2048.f) + bv;
            }
        if (tl < 3) __syncthreads();
    }
}

// ---------------------------------------------------------------------------
// Recurrence: 128 blocks x 512 thr. Block owns 32 gate rows (8 units).
// W_hh split from fp32 into VGPR frags once per dispatch. h slots t-indexed
// (slot 0 = zeros, slot t+1 = h_t): consumers use NORMAL L2-cached loads
// (write-once per launch); producers do dense relaxed-atomic u32 stores
// (writethrough to L3) after LDS transpose. Flags barrier, no fences.
__global__ __launch_bounds__(512, 1) void rec_kernel(
    const float* __restrict__ Whh, const float* __restrict__ xpseg,
    u32* hbuf, float* __restrict__ cT, int* flags, int t0, int seg, int layer) {
    __shared__ float scr[8][32][66];
    __shared__ u32 hx[8 * 72];
    const int tid = threadIdx.x, bid = blockIdx.x;
    const int l = tid & 63, w = tid >> 6;
    const int arow = l & 15, akg = l >> 4;
    const int eb = l;

    // ---- A (W_hh) fragments from fp32: wave w owns k in [w*128, +128)
    f16x8 Ah[2][4], Al[2][4];
#pragma unroll
    for (int m = 0; m < 2; ++m) {
        const int rp = bid * 32 + m * 16 + arow;
        const float* src0 = Whh + (size_t)((rp & 3) * H + (rp >> 2)) * H;
#pragma unroll
        for (int c = 0; c < 4; ++c) {
            int kk = w * 128 + c * 32 + akg * 8;
            float4 v0 = *(const float4*)(src0 + kk);
            float4 v1 = *(const float4*)(src0 + kk + 4);
            split8(v0, v1, Ah[m][c], Al[m][c]);
        }
    }

    float cs = (t0 > 0) ? cT[(size_t)(bid * 8 + w) * 64 + eb] : 0.f;

    for (int t = t0; t < t0 + seg; ++t) {
        const u32* hin = hbuf + (size_t)t * SLOT;

        float xpv[4];
        {
            const float* xb = xpseg + ((size_t)(t - t0) * 4096 + bid * 32 + w * 4) * 64 + eb;
#pragma unroll
            for (int g = 0; g < 4; ++g) xpv[g] = xb[g * 64];
        }

        f32x4 acch[2][4], accl[2][4];
#pragma unroll
        for (int m = 0; m < 2; ++m)
#pragma unroll
            for (int ns = 0; ns < 4; ++ns) { acch[m][ns] = (f32x4){0,0,0,0}; accl[m][ns] = (f32x4){0,0,0,0}; }

        u64 raw[2][4][4];
#pragma unroll
        for (int ns = 0; ns < 4; ++ns) {
            const u32* bp = hin + (size_t)((w * 4 + 0) * 4 + akg) * 512 + (ns * 16 + arow) * 8;
            *(uint4*)&raw[0][ns][0] = *(const uint4*)bp;
            *(uint4*)&raw[0][ns][2] = *(const uint4*)(bp + 4);
        }
#pragma unroll
        for (int c = 0; c < 4; ++c) {
            const int cur = c & 1;
            if (c < 3) {
#pragma unroll
                for (int ns = 0; ns < 4; ++ns) {
                    const u32* bp = hin + (size_t)((w * 4 + c + 1) * 4 + akg) * 512 + (ns * 16 + arow) * 8;
                    *(uint4*)&raw[cur ^ 1][ns][0] = *(const uint4*)bp;
                    *(uint4*)&raw[cur ^ 1][ns][2] = *(const uint4*)(bp + 4);
                }
            }
#pragma unroll
            for (int ns = 0; ns < 4; ++ns) {
                f16x8 bh, bl;
                unpack8(raw[cur][ns], bh, bl);
#pragma unroll
                for (int m = 0; m < 2; ++m) {
                    acch[m][ns] = MFMA16(Ah[m][c], bh, acch[m][ns], 0, 0, 0);
                    accl[m][ns] = MFMA16(Ah[m][c], bl, accl[m][ns], 0, 0, 0);
                    accl[m][ns] = MFMA16(Al[m][c], bh, accl[m][ns], 0, 0, 0);
                }
            }
        }
        // ---- partial-K reduce via LDS
#pragma unroll
        for (int m = 0; m < 2; ++m)
#pragma unroll
            for (int ns = 0; ns < 4; ++ns)
#pragma unroll
                for (int r = 0; r < 4; ++r)
                    scr[w][m * 16 + akg * 4 + r][ns * 16 + arow] =
                        acch[m][ns][r] + accl[m][ns][r] * (1.f / 2048.f);
        __syncthreads();

        // ---- epilogue: thread (unit=w, batch=eb)
        {
            float gg[4];
#pragma unroll
            for (int g = 0; g < 4; ++g) {
                int rl = w * 4 + g;
                float s = 0.f;
#pragma unroll
                for (int ww = 0; ww < 8; ++ww) s += scr[ww][rl][eb];
                gg[g] = s + xpv[g];
            }
            float is = sigm(gg[0]), fs = sigm(gg[1]), gt = tanhf_(gg[2]), os = sigm(gg[3]);
            cs = fs * cs + is * gt;
            float hnew = os * tanhf_(cs);
            hx[w * 72 + eb] = packu(hnew);
        }
        __syncthreads();

        // ---- dense store: block's 512 values -> contiguous 2KB at slot t+1
        {
            u32 pko = hx[(tid & 7) * 72 + (tid >> 3)];
            __hip_atomic_store(&hbuf[(size_t)(t + 1) * SLOT + bid * 512 + tid], pko,
                               __ATOMIC_RELAXED, SCOPE_AGENT);
        }
        __syncthreads();   // all waves' stores vmcnt-drained before flag

        if (t != t0 + seg - 1) {
            const int target = layer * TT + t + 1;
            if (w == 0) {
                if (l == 0)
                    __hip_atomic_store(&flags[bid], target, __ATOMIC_RELEASE, SCOPE_AGENT);
                bool done = false;
                while (!done) {
                    int m0 = __hip_atomic_load(&flags[l], __ATOMIC_RELAXED, SCOPE_AGENT);
                    int m1 = __hip_atomic_load(&flags[l + 64], __ATOMIC_RELAXED, SCOPE_AGENT);
                    int mn = m0 < m1 ? m0 : m1;
                    done = __all(mn >= target);
                    if (!done) __builtin_amdgcn_s_sleep(1);
                }
            }
            __builtin_amdgcn_sched_barrier(0);
            __syncthreads();
        }
    }
    cT[(size_t)(bid * 8 + w) * 64 + eb] = cs;
}

// ---------------------------------------------------------------------------
// out[b][o] = sum_j h[j][b] * Wfc[o][j] + bfc[o]; h from hs1 slot 256
__global__ __launch_bounds__(256) void fc_kernel(
    const u32* __restrict__ hp, const float* __restrict__ Wfc,
    const float* __restrict__ bfc, float* __restrict__ out) {
    const int tid = threadIdx.x;
    const int b = tid & 63;
    const int o = blockIdx.x * 4 + (tid >> 6);
    const float* wr = Wfc + (size_t)o * H;
    float acc = 0.f;
    for (int jb = 0; jb < 128; ++jb) {
        const u64* bp = (const u64*)(hp + (size_t)jb * 512 + b * 8);
        u64 raw[4] = {bp[0], bp[1], bp[2], bp[3]};
        f16x8 vh, vl;
        unpack8(raw, vh, vl);
#pragma unroll
        for (int e = 0; e < 8; ++e) {
            float hv = (float)vh[e] + (float)vl[e] * (1.f / 2048.f);
            acc += hv * wr[jb * 8 + e];
        }
    }
    out[(size_t)b * 512 + o] = acc + bfc[o];
}

// ---------------------------------------------------------------------------
extern "C" void kernel_launch(void* const* d_in, const int* in_sizes, int n_in,
                              void* d_out, int out_size, void* d_ws, size_t ws_size,
                              hipStream_t stream) {
    const float* x    = (const float*)d_in[0];
    const float* Wih0 = (const float*)d_in[1];
    const float* Whh0 = (const float*)d_in[2];
    const float* b0   = (const float*)d_in[3];
    const float* Wih1 = (const float*)d_in[4];
    const float* Whh1 = (const float*)d_in[5];
    const float* b1   = (const float*)d_in[6];
    const float* Wfc  = (const float*)d_in[7];
    const float* bfc  = (const float*)d_in[8];
    float* out = (float*)d_out;

    // fixed u32: ys 257*SLOT + hs1 257*SLOT + xpack 256*XSLOT + cT + flags
    const size_t fixed_bytes =
        ((size_t)257 * SLOT * 2 + (size_t)256 * XSLOT + 65536 + 128) * 4;  // ~168.6 MB
    int SEG = 128;
    while (SEG > 8 && fixed_bytes + (size_t)SEG * 1048576 > ws_size) SEG >>= 1;

    char* p = (char*)d_ws;
    u32* ys      = (u32*)p;   p += (size_t)257 * SLOT * 4;
    u32* hs1     = (u32*)p;   p += (size_t)257 * SLOT * 4;
    u32* xpack   = (u32*)p;   p += (size_t)256 * XSLOT * 4;
    float* xpseg = (float*)p; p += (size_t)SEG * 1048576;
    float* cT    = (float*)p; p += 262144;
    int* flags   = (int*)p;

    // zero slot-0 of ys/hs1 + flags (every launch: flags must restart at 0)
    zero_kernel<<<SLOT / 256, 256, 0, stream>>>(ys, SLOT);
    zero_kernel<<<SLOT / 256, 256, 0, stream>>>(hs1, SLOT);
    zero_kernel<<<1, 256, 0, stream>>>((u32*)flags, 128);

    xT_kernel<<<TT, 512, 0, stream>>>(x, xpack);

    const int nseg = TT / SEG;
    for (int layer = 0; layer < 2; ++layer) {
        for (int s = 0; s < nseg; ++s) {
            int t0 = s * SEG;
            if (layer == 0)
                xp_gemm<0><<<dim3(16, SEG / 4), 512, 0, stream>>>(Wih0, b0, xpack, xpseg, t0);
            else
                xp_gemm<1><<<dim3(16, SEG / 4), 512, 0, stream>>>(Wih1, b1, ys, xpseg, t0);
            rec_kernel<<<RECBLK, 512, 0, stream>>>(
                layer ? Whh1 : Whh0, xpseg, layer ? hs1 : ys, cT, flags, t0, SEG, layer);
        }
    }
    fc_kernel<<<128, 256, 0, stream>>>(hs1 + (size_t)256 * SLOT, Wfc, bfc, out);
}

// Round 9
// 5209.511 us; speedup vs baseline: 5.7854x; 1.1361x over previous
//
#include <hip/hip_runtime.h>
#include <math.h>

#define BATCH 64
#define TT 256
#define IN_DIM 512
#define H 1024
#define SLOT 65536   // u32 per h slot (1024 j x 64 b)
#define XSLOT 32768  // u32 per x slot

typedef __attribute__((ext_vector_type(8))) _Float16 f16x8;
typedef __attribute__((ext_vector_type(4))) float f32x4;
typedef unsigned int u32;
typedef unsigned long long u64;

#define MFMA16 __builtin_amdgcn_mfma_f32_16x16x32_f16
#define SCOPE_AGENT __HIP_MEMORY_SCOPE_AGENT

union FB { u32 u[4]; f16x8 v; };

__device__ __forceinline__ float sigm(float v) { return 1.f / (1.f + __expf(-v)); }
__device__ __forceinline__ float tanhf_(float v) {
    float e = __expf(-2.f * fabsf(v));
    float r = (1.f - e) / (1.f + e);
    return v < 0.f ? -r : r;
}
__device__ __forceinline__ void split16(float v, _Float16& hi, _Float16& lo) {
    hi = (_Float16)v;
    lo = (_Float16)((v - (float)hi) * 2048.0f);
}
__device__ __forceinline__ u32 packu(float v) {
    _Float16 hi, lo; split16(v, hi, lo);
    return (u32)__builtin_bit_cast(unsigned short, hi)
         | ((u32)__builtin_bit_cast(unsigned short, lo) << 16);
}
__device__ __forceinline__ void unpack8(const u64* r, f16x8& bh, f16x8& bl) {
    FB Hf, Lf;
#pragma unroll
    for (int i = 0; i < 4; ++i) {
        u32 p0 = (u32)r[i], p1 = (u32)(r[i] >> 32);
        Hf.u[i] = __builtin_amdgcn_perm(p1, p0, 0x05040100u);
        Lf.u[i] = __builtin_amdgcn_perm(p1, p0, 0x07060302u);
    }
    bh = Hf.v; bl = Lf.v;
}
__device__ __forceinline__ void split8(const float4& a0, const float4& a1, f16x8& hi, f16x8& lo) {
    float tmp[8] = {a0.x, a0.y, a0.z, a0.w, a1.x, a1.y, a1.z, a1.w};
#pragma unroll
    for (int e = 0; e < 8; ++e) { _Float16 h_, l_; split16(tmp[e], h_, l_); hi[e] = h_; lo[e] = l_; }
}

// ---------------------------------------------------------------------------
__global__ void zero_kernel(u32* __restrict__ p, int n) {
    int i = blockIdx.x * 256 + threadIdx.x;
    if (i < n) p[i] = 0u;
}

// ---------------------------------------------------------------------------
// x[b][t][k] fp32 -> xpack[t][(k>>3)*512 + b*8 + (k&7)] packed u32
__global__ __launch_bounds__(512) void xT_kernel(
    const float* __restrict__ x, u32* __restrict__ xpack) {
    const int tid = threadIdx.x, t = blockIdx.x;
    const int b = tid & 63, kq = tid >> 6;
#pragma unroll
    for (int kb = 0; kb < 8; ++kb) {
        int k = kb * 64 + kq * 8;
        const float* src = x + ((size_t)b * TT + t) * IN_DIM + k;
        float4 v0 = *(const float4*)src;
        float4 v1 = *(const float4*)(src + 4);
        u32 o[8] = {packu(v0.x), packu(v0.y), packu(v0.z), packu(v0.w),
                    packu(v1.x), packu(v1.y), packu(v1.z), packu(v1.w)};
        u32* dst = xpack + (size_t)t * XSLOT + (kb * 8 + kq) * 512 + b * 8;
        *(uint4*)dst = make_uint4(o[0], o[1], o[2], o[3]);
        *(uint4*)(dst + 4) = make_uint4(o[4], o[5], o[6], o[7]);
    }
}

// ---------------------------------------------------------------------------
// Fused staggered 2-layer recurrence body.
// gates = Wcat[rp]·concat(xinput[K=KX], h_prev[K=1024]) + bias
// NC = (KX+1024)/32/8 chunks per wave; DEP=1 => layer 1 (x = ys[t+1], dep on flags0)
template<int NC, int KX, int XS, int DEP>
__device__ __forceinline__ void rec_body(
    const float* __restrict__ Wih, const float* __restrict__ Whh,
    const float* __restrict__ bias, const u32* __restrict__ xbuf,
    u32* hbuf, int* ownflags, int* depflags,
    float (*scr)[32][80], u32* hx, int gbid) {
    const int tid = threadIdx.x;
    const int l = tid & 63, w = tid >> 6;
    const int arow = l & 15, akg = l >> 4;
    const int eb = l;
    const int KC = NC * 32;

    // ---- W fragments (split f16 hi/lo) for wave's k-slice [w*KC, w*KC+KC)
    f16x8 Ah[2][NC], Al[2][NC];
#pragma unroll
    for (int m = 0; m < 2; ++m) {
        const int rp = gbid * 32 + m * 16 + arow;
        const float* wihrow = Wih + (size_t)((rp & 3) * H + (rp >> 2)) * KX;
        const float* whhrow = Whh + (size_t)((rp & 3) * H + (rp >> 2)) * H;
#pragma unroll
        for (int c = 0; c < NC; ++c) {
            int g = w * KC + c * 32 + akg * 8;
            const float* src = (g < KX) ? (wihrow + g) : (whhrow + (g - KX));
            float4 v0 = *(const float4*)src;
            float4 v1 = *(const float4*)(src + 4);
            split8(v0, v1, Ah[m][c], Al[m][c]);
        }
    }

    float cs = 0.f;

    for (int t = 0; t < TT; ++t) {
        // ---- wait: own group at step t (h slot t ready), dep (layer0) at t+1
        if (DEP || t > 0) {
            if (w == 0) {
                bool done = false;
                while (!done) {
                    int o0 = __hip_atomic_load(&ownflags[l], __ATOMIC_RELAXED, SCOPE_AGENT);
                    int o1 = __hip_atomic_load(&ownflags[l + 64], __ATOMIC_RELAXED, SCOPE_AGENT);
                    bool ok = ((o0 < o1 ? o0 : o1) >= t);
                    if (DEP) {
                        int d0 = __hip_atomic_load(&depflags[l], __ATOMIC_RELAXED, SCOPE_AGENT);
                        int d1 = __hip_atomic_load(&depflags[l + 64], __ATOMIC_RELAXED, SCOPE_AGENT);
                        ok = ok && ((d0 < d1 ? d0 : d1) >= t + 1);
                    }
                    done = __all(ok);
                    if (!done) __builtin_amdgcn_s_sleep(1);
                }
            }
            __builtin_amdgcn_sched_barrier(0);
            __syncthreads();
        }

        const u32* xb = xbuf + (size_t)(DEP ? t + 1 : t) * XS;
        const u32* hb = hbuf + (size_t)t * SLOT;

        f32x4 acch[2][4], accl[2][4];
#pragma unroll
        for (int m = 0; m < 2; ++m)
#pragma unroll
            for (int ns = 0; ns < 4; ++ns) { acch[m][ns] = (f32x4){0,0,0,0}; accl[m][ns] = (f32x4){0,0,0,0}; }

#pragma unroll
        for (int c = 0; c < NC; ++c) {
            const int g0 = w * KC + c * 32;
            const u32* cb = (g0 < KX) ? (xb + (size_t)(g0 >> 3) * 512)
                                      : (hb + (size_t)((g0 - KX) >> 3) * 512);
            u64 raw[4][4];
#pragma unroll
            for (int ns = 0; ns < 4; ++ns) {
                const u32* bp = cb + akg * 512 + (ns * 16 + arow) * 8;
                *(uint4*)&raw[ns][0] = *(const uint4*)bp;
                *(uint4*)&raw[ns][2] = *(const uint4*)(bp + 4);
            }
#pragma unroll
            for (int ns = 0; ns < 4; ++ns) {
                f16x8 bh, bl;
                unpack8(raw[ns], bh, bl);
#pragma unroll
                for (int m = 0; m < 2; ++m) {
                    acch[m][ns] = MFMA16(Ah[m][c], bh, acch[m][ns], 0, 0, 0);
                    accl[m][ns] = MFMA16(Ah[m][c], bl, accl[m][ns], 0, 0, 0);
                    accl[m][ns] = MFMA16(Al[m][c], bh, accl[m][ns], 0, 0, 0);
                }
            }
        }
        // ---- partial-K reduce via LDS
#pragma unroll
        for (int m = 0; m < 2; ++m)
#pragma unroll
            for (int ns = 0; ns < 4; ++ns)
#pragma unroll
                for (int r = 0; r < 4; ++r)
                    scr[w][m * 16 + akg * 4 + r][ns * 16 + arow] =
                        acch[m][ns][r] + accl[m][ns][r] * (1.f / 2048.f);
        __syncthreads();

        // ---- epilogue: thread (unit=w, batch=eb)
        {
            float gg[4];
#pragma unroll
            for (int g = 0; g < 4; ++g) {
                int rl = w * 4 + g;
                float s = 0.f;
#pragma unroll
                for (int ww = 0; ww < 8; ++ww) s += scr[ww][rl][eb];
                int rp = gbid * 32 + rl;
                gg[g] = s + bias[(rp & 3) * H + (rp >> 2)];
            }
            float is = sigm(gg[0]), fs = sigm(gg[1]), gt = tanhf_(gg[2]), os = sigm(gg[3]);
            cs = fs * cs + is * gt;
            float hnew = os * tanhf_(cs);
            hx[w * 72 + eb] = packu(hnew);
        }
        __syncthreads();

        // ---- dense store: block's 512 values -> contiguous 2KB at slot t+1
        {
            u32 pko = hx[(tid & 7) * 72 + (tid >> 3)];
            __hip_atomic_store(&hbuf[(size_t)(t + 1) * SLOT + gbid * 512 + tid], pko,
                               __ATOMIC_RELAXED, SCOPE_AGENT);
        }
        __syncthreads();   // all waves' stores vmcnt-drained before flag
        if (tid == 0)
            __hip_atomic_store(&ownflags[gbid], t + 1, __ATOMIC_RELEASE, SCOPE_AGENT);
    }
}

// ---------------------------------------------------------------------------
// 256 blocks x 512 thr, 1 block/CU (84KB LDS) => all co-resident.
// Blocks 0..127: layer 0 (x from xpack, K=1536). Blocks 128..255: layer 1
// (x from ys slots, K=2048), staggered one step behind layer 0.
__global__ __launch_bounds__(512, 1) void rec_fused(
    const float* __restrict__ Wih0, const float* __restrict__ Whh0, const float* __restrict__ b0,
    const float* __restrict__ Wih1, const float* __restrict__ Whh1, const float* __restrict__ b1,
    const u32* __restrict__ xpack, u32* ys, u32* hs1, int* flags0, int* flags1) {
    __shared__ float scr[8][32][80];
    __shared__ u32 hx[8 * 72];
    const int bid = blockIdx.x;
    if (bid < 128)
        rec_body<6, 512, XSLOT, 0>(Wih0, Whh0, b0, xpack, ys, flags0, nullptr, scr, hx, bid);
    else
        rec_body<8, 1024, SLOT, 1>(Wih1, Whh1, b1, ys, hs1, flags1, flags0, scr, hx, bid - 128);
}

// ---------------------------------------------------------------------------
// out[b][o] = sum_j h[j][b] * Wfc[o][j] + bfc[o]; h from hs1 slot 256
__global__ __launch_bounds__(256) void fc_kernel(
    const u32* __restrict__ hp, const float* __restrict__ Wfc,
    const float* __restrict__ bfc, float* __restrict__ out) {
    const int tid = threadIdx.x;
    const int b = tid & 63;
    const int o = blockIdx.x * 4 + (tid >> 6);
    const float* wr = Wfc + (size_t)o * H;
    float acc = 0.f;
    for (int jb = 0; jb < 128; ++jb) {
        const u64* bp = (const u64*)(hp + (size_t)jb * 512 + b * 8);
        u64 raw[4] = {bp[0], bp[1], bp[2], bp[3]};
        f16x8 vh, vl;
        unpack8(raw, vh, vl);
#pragma unroll
        for (int e = 0; e < 8; ++e) {
            float hv = (float)vh[e] + (float)vl[e] * (1.f / 2048.f);
            acc += hv * wr[jb * 8 + e];
        }
    }
    out[(size_t)b * 512 + o] = acc + bfc[o];
}

// ---------------------------------------------------------------------------
extern "C" void kernel_launch(void* const* d_in, const int* in_sizes, int n_in,
                              void* d_out, int out_size, void* d_ws, size_t ws_size,
                              hipStream_t stream) {
    const float* x    = (const float*)d_in[0];
    const float* Wih0 = (const float*)d_in[1];
    const float* Whh0 = (const float*)d_in[2];
    const float* b0   = (const float*)d_in[3];
    const float* Wih1 = (const float*)d_in[4];
    const float* Whh1 = (const float*)d_in[5];
    const float* b1   = (const float*)d_in[6];
    const float* Wfc  = (const float*)d_in[7];
    const float* bfc  = (const float*)d_in[8];
    float* out = (float*)d_out;

    // ws (u32): ys 257*SLOT | hs1 257*SLOT | xpack 256*XSLOT | flags0[128] flags1[128]
    char* p = (char*)d_ws;
    u32* ys     = (u32*)p; p += (size_t)257 * SLOT * 4;
    u32* hs1    = (u32*)p; p += (size_t)257 * SLOT * 4;
    u32* xpack  = (u32*)p; p += (size_t)256 * XSLOT * 4;
    int* flags0 = (int*)p; p += 512;
    int* flags1 = (int*)p;

    // zero slot-0 of ys/hs1 + both flag arrays (every launch)
    zero_kernel<<<SLOT / 256, 256, 0, stream>>>(ys, SLOT);
    zero_kernel<<<SLOT / 256, 256, 0, stream>>>(hs1, SLOT);
    zero_kernel<<<1, 256, 0, stream>>>((u32*)flags0, 256);

    xT_kernel<<<TT, 512, 0, stream>>>(x, xpack);

    rec_fused<<<256, 512, 0, stream>>>(
        Wih0, Whh0, b0, Wih1, Whh1, b1, xpack, ys, hs1, flags0, flags1);

    fc_kernel<<<128, 256, 0, stream>>>(hs1 + (size_t)256 * SLOT, Wfc, bfc, out);
}

// Round 10
// 4569.908 us; speedup vs baseline: 6.5951x; 1.1400x over previous
//
#include <hip/hip_runtime.h>
#include <math.h>

#define BATCH 64
#define TT 256
#define IN_DIM 512
#define H 1024
#define SLOT 65536   // u32 per h slot (1024 j x 64 b)
#define XSLOT 32768  // u32 per x slot

typedef __attribute__((ext_vector_type(8))) _Float16 f16x8;
typedef __attribute__((ext_vector_type(4))) float f32x4;
typedef unsigned int u32;
typedef unsigned long long u64;

#define MFMA16 __builtin_amdgcn_mfma_f32_16x16x32_f16
#define SCOPE_AGENT __HIP_MEMORY_SCOPE_AGENT

union FB { u32 u[4]; f16x8 v; };

__device__ __forceinline__ float sigm(float v) { return 1.f / (1.f + __expf(-v)); }
__device__ __forceinline__ float tanhf_(float v) {
    float e = __expf(-2.f * fabsf(v));
    float r = (1.f - e) / (1.f + e);
    return v < 0.f ? -r : r;
}
// B-side pack: stored pair (hi = f16(32u), lo = f16(32u - hi)); u = (hi+lo)/32
__device__ __forceinline__ u32 packu(float v) {
    float s = v * 32.f;
    _Float16 hi = (_Float16)s;
    _Float16 lo = (_Float16)(s - (float)hi);
    return (u32)__builtin_bit_cast(unsigned short, hi)
         | ((u32)__builtin_bit_cast(unsigned short, lo) << 16);
}
__device__ __forceinline__ void unpack8(const u64* r, f16x8& bh, f16x8& bl) {
    FB Hf, Lf;
#pragma unroll
    for (int i = 0; i < 4; ++i) {
        u32 p0 = (u32)r[i], p1 = (u32)(r[i] >> 32);
        Hf.u[i] = __builtin_amdgcn_perm(p1, p0, 0x05040100u);
        Lf.u[i] = __builtin_amdgcn_perm(p1, p0, 0x07060302u);
    }
    bh = Hf.v; bl = Lf.v;
}
// W-side split: hi = f16(64W), lo = f16(64W - hi).
// Products: hi_W*hi_B + hi_W*lo_B + lo_W*hi_B all at scale 2048*W*u -> one acc.
__device__ __forceinline__ void wsplit8(const float4& a0, const float4& a1, f16x8& hi, f16x8& lo) {
    float tmp[8] = {a0.x, a0.y, a0.z, a0.w, a1.x, a1.y, a1.z, a1.w};
#pragma unroll
    for (int e = 0; e < 8; ++e) {
        float s = tmp[e] * 64.f;
        _Float16 h_ = (_Float16)s;
        hi[e] = h_;
        lo[e] = (_Float16)(s - (float)h_);
    }
}

// ---------------------------------------------------------------------------
__global__ void zero_kernel(u32* __restrict__ p, int n) {
    int i = blockIdx.x * 256 + threadIdx.x;
    if (i < n) p[i] = 0u;
}

// ---------------------------------------------------------------------------
// x[b][t][k] fp32 -> xpack[t][(k>>3)*512 + b*8 + (k&7)] packed u32
__global__ __launch_bounds__(512) void xT_kernel(
    const float* __restrict__ x, u32* __restrict__ xpack) {
    const int tid = threadIdx.x, t = blockIdx.x;
    const int b = tid & 63, kq = tid >> 6;
#pragma unroll
    for (int kb = 0; kb < 8; ++kb) {
        int k = kb * 64 + kq * 8;
        const float* src = x + ((size_t)b * TT + t) * IN_DIM + k;
        float4 v0 = *(const float4*)src;
        float4 v1 = *(const float4*)(src + 4);
        u32 o[8] = {packu(v0.x), packu(v0.y), packu(v0.z), packu(v0.w),
                    packu(v1.x), packu(v1.y), packu(v1.z), packu(v1.w)};
        u32* dst = xpack + (size_t)t * XSLOT + (kb * 8 + kq) * 512 + b * 8;
        *(uint4*)dst = make_uint4(o[0], o[1], o[2], o[3]);
        *(uint4*)(dst + 4) = make_uint4(o[4], o[5], o[6], o[7]);
    }
}

// ---------------------------------------------------------------------------
// Fused staggered 2-layer recurrence body.
// gates = (1/2048)*S + bias, S = Wcat_frag . concat(x, h_prev) in scaled f16.
template<int NC, int KX, int XS, int DEP>
__device__ __forceinline__ void rec_body(
    const float* __restrict__ Wih, const float* __restrict__ Whh,
    const float* __restrict__ bias, const u32* __restrict__ xbuf,
    u32* hbuf, int* ownflags, int* depflags,
    float (*scr)[32][66], u32* hx, int gbid) {
    const int tid = threadIdx.x;
    const int l = tid & 63, w = tid >> 6;
    const int arow = l & 15, akg = l >> 4;
    const int eb = l;
    const int KC = NC * 32;

    // ---- W fragments (scaled split f16) for wave's k-slice [w*KC, w*KC+KC)
    f16x8 Ah[2][NC], Al[2][NC];
#pragma unroll
    for (int m = 0; m < 2; ++m) {
        const int rp = gbid * 32 + m * 16 + arow;
        const float* wihrow = Wih + (size_t)((rp & 3) * H + (rp >> 2)) * KX;
        const float* whhrow = Whh + (size_t)((rp & 3) * H + (rp >> 2)) * H;
#pragma unroll
        for (int c = 0; c < NC; ++c) {
            int g = w * KC + c * 32 + akg * 8;
            const float* src = (g < KX) ? (wihrow + g) : (whhrow + (g - KX));
            float4 v0 = *(const float4*)src;
            float4 v1 = *(const float4*)(src + 4);
            wsplit8(v0, v1, Ah[m][c], Al[m][c]);
        }
    }
    // ---- per-chunk B offsets (in-slot u32 index) + source selector
    int boff[NC];
    bool bh_[NC];
#pragma unroll
    for (int c = 0; c < NC; ++c) {
        int g0 = w * KC + c * 32;
        bool ish = (g0 >= KX);
        int gl = ish ? (g0 - KX) : g0;
        boff[c] = (gl >> 3) * 512 + akg * 512 + arow * 8;
        bh_[c] = ish;
    }
    // ---- bias (hoisted)
    float gbias[4];
#pragma unroll
    for (int g = 0; g < 4; ++g) {
        int rp = gbid * 32 + w * 4 + g;
        gbias[g] = bias[(rp & 3) * H + (rp >> 2)];
    }

    float cs = 0.f;

    for (int t = 0; t < TT; ++t) {
        if (DEP || t > 0) {
            if (w == 0) {
                bool done = false;
                while (!done) {
                    int o0 = __hip_atomic_load(&ownflags[l], __ATOMIC_RELAXED, SCOPE_AGENT);
                    int o1 = __hip_atomic_load(&ownflags[l + 64], __ATOMIC_RELAXED, SCOPE_AGENT);
                    bool ok = ((o0 < o1 ? o0 : o1) >= t);
                    if (DEP) {
                        int d0 = __hip_atomic_load(&depflags[l], __ATOMIC_RELAXED, SCOPE_AGENT);
                        int d1 = __hip_atomic_load(&depflags[l + 64], __ATOMIC_RELAXED, SCOPE_AGENT);
                        ok = ok && ((d0 < d1 ? d0 : d1) >= t + 1);
                    }
                    done = __all(ok);
                    if (!done) __builtin_amdgcn_s_sleep(1);
                }
            }
            __builtin_amdgcn_sched_barrier(0);
            __syncthreads();
        }

        const u32* xb = xbuf + (size_t)(DEP ? t + 1 : t) * XS;
        const u32* hb = hbuf + (size_t)t * SLOT;

        f32x4 acc[2][4];
#pragma unroll
        for (int m = 0; m < 2; ++m)
#pragma unroll
            for (int ns = 0; ns < 4; ++ns) acc[m][ns] = (f32x4){0.f, 0.f, 0.f, 0.f};

#pragma unroll
        for (int c = 0; c < NC; ++c) {
            const u32* bp0 = (bh_[c] ? hb : xb) + boff[c];
            u64 raw[4][4];
#pragma unroll
            for (int ns = 0; ns < 4; ++ns) {
                const u32* bp = bp0 + ns * 128;
                *(uint4*)&raw[ns][0] = *(const uint4*)bp;
                *(uint4*)&raw[ns][2] = *(const uint4*)(bp + 4);
            }
#pragma unroll
            for (int ns = 0; ns < 4; ++ns) {
                f16x8 bh, bl;
                unpack8(raw[ns], bh, bl);
#pragma unroll
                for (int m = 0; m < 2; ++m) {
                    acc[m][ns] = MFMA16(Ah[m][c], bh, acc[m][ns], 0, 0, 0);
                    acc[m][ns] = MFMA16(Ah[m][c], bl, acc[m][ns], 0, 0, 0);
                    acc[m][ns] = MFMA16(Al[m][c], bh, acc[m][ns], 0, 0, 0);
                }
            }
        }
        // ---- partial-K reduce via LDS (stride 66: <=2-way conflicts)
#pragma unroll
        for (int m = 0; m < 2; ++m)
#pragma unroll
            for (int ns = 0; ns < 4; ++ns)
#pragma unroll
                for (int r = 0; r < 4; ++r)
                    scr[w][m * 16 + akg * 4 + r][ns * 16 + arow] = acc[m][ns][r];
        __syncthreads();

        // ---- epilogue: thread (unit=w, batch=eb)
        {
            float gg[4];
#pragma unroll
            for (int g = 0; g < 4; ++g) {
                int rl = w * 4 + g;
                float s = 0.f;
#pragma unroll
                for (int ww = 0; ww < 8; ++ww) s += scr[ww][rl][eb];
                gg[g] = s * (1.f / 2048.f) + gbias[g];
            }
            float is = sigm(gg[0]), fs = sigm(gg[1]), gt = tanhf_(gg[2]), os = sigm(gg[3]);
            cs = fs * cs + is * gt;
            float hnew = os * tanhf_(cs);
            hx[w * 72 + eb] = packu(hnew);
        }
        __syncthreads();

        // ---- dense store: block's 512 values -> contiguous 2KB at slot t+1
        {
            u32 pko = hx[(tid & 7) * 72 + (tid >> 3)];
            __hip_atomic_store(&hbuf[(size_t)(t + 1) * SLOT + gbid * 512 + tid], pko,
                               __ATOMIC_RELAXED, SCOPE_AGENT);
        }
        __syncthreads();   // all waves' stores vmcnt-drained before flag
        if (tid == 0)
            __hip_atomic_store(&ownflags[gbid], t + 1, __ATOMIC_RELEASE, SCOPE_AGENT);
    }
}

// ---------------------------------------------------------------------------
// 256 blocks x 512 thr, 1 block/CU. Blocks 0..127: layer 0 (x: xpack, K=1536).
// Blocks 128..255: layer 1 (x: ys slots, K=2048), staggered one step behind.
// __launch_bounds__(512,2): 2 waves/EU => VGPR cap 256 so W frags stay resident.
__global__ __launch_bounds__(512, 2) void rec_fused(
    const float* __restrict__ Wih0, const float* __restrict__ Whh0, const float* __restrict__ b0,
    const float* __restrict__ Wih1, const float* __restrict__ Whh1, const float* __restrict__ b1,
    const u32* __restrict__ xpack, u32* ys, u32* hs1, int* flags0, int* flags1) {
    __shared__ float scr[8][32][66];
    __shared__ u32 hx[8 * 72];
    const int bid = blockIdx.x;
    if (bid < 128)
        rec_body<6, 512, XSLOT, 0>(Wih0, Whh0, b0, xpack, ys, flags0, nullptr, scr, hx, bid);
    else
        rec_body<8, 1024, SLOT, 1>(Wih1, Whh1, b1, ys, hs1, flags1, flags0, scr, hx, bid - 128);
}

// ---------------------------------------------------------------------------
// out[b][o] = sum_j h[j][b] * Wfc[o][j] + bfc[o]; h from hs1 slot 256
__global__ __launch_bounds__(256) void fc_kernel(
    const u32* __restrict__ hp, const float* __restrict__ Wfc,
    const float* __restrict__ bfc, float* __restrict__ out) {
    const int tid = threadIdx.x;
    const int b = tid & 63;
    const int o = blockIdx.x * 4 + (tid >> 6);
    const float* wr = Wfc + (size_t)o * H;
    float acc = 0.f;
    for (int jb = 0; jb < 128; ++jb) {
        const u64* bp = (const u64*)(hp + (size_t)jb * 512 + b * 8);
        u64 raw[4] = {bp[0], bp[1], bp[2], bp[3]};
        f16x8 vh, vl;
        unpack8(raw, vh, vl);
#pragma unroll
        for (int e = 0; e < 8; ++e) {
            float hv = ((float)vh[e] + (float)vl[e]) * (1.f / 32.f);
            acc += hv * wr[jb * 8 + e];
        }
    }
    out[(size_t)b * 512 + o] = acc + bfc[o];
}

// ---------------------------------------------------------------------------
extern "C" void kernel_launch(void* const* d_in, const int* in_sizes, int n_in,
                              void* d_out, int out_size, void* d_ws, size_t ws_size,
                              hipStream_t stream) {
    const float* x    = (const float*)d_in[0];
    const float* Wih0 = (const float*)d_in[1];
    const float* Whh0 = (const float*)d_in[2];
    const float* b0   = (const float*)d_in[3];
    const float* Wih1 = (const float*)d_in[4];
    const float* Whh1 = (const float*)d_in[5];
    const float* b1   = (const float*)d_in[6];
    const float* Wfc  = (const float*)d_in[7];
    const float* bfc  = (const float*)d_in[8];
    float* out = (float*)d_out;

    // ws (u32): ys 257*SLOT | hs1 257*SLOT | xpack 256*XSLOT | flags0[128] flags1[128]
    char* p = (char*)d_ws;
    u32* ys     = (u32*)p; p += (size_t)257 * SLOT * 4;
    u32* hs1    = (u32*)p; p += (size_t)257 * SLOT * 4;
    u32* xpack  = (u32*)p; p += (size_t)256 * XSLOT * 4;
    int* flags0 = (int*)p; p += 512;
    int* flags1 = (int*)p;

    // zero slot-0 of ys/hs1 + both flag arrays (every launch)
    zero_kernel<<<SLOT / 256, 256, 0, stream>>>(ys, SLOT);
    zero_kernel<<<SLOT / 256, 256, 0, stream>>>(hs1, SLOT);
    zero_kernel<<<1, 256, 0, stream>>>((u32*)flags0, 256);

    xT_kernel<<<TT, 512, 0, stream>>>(x, xpack);

    rec_fused<<<256, 512, 0, stream>>>(
        Wih0, Whh0, b0, Wih1, Whh1, b1, xpack, ys, hs1, flags0, flags1);

    fc_kernel<<<128, 256, 0, stream>>>(hs1 + (size_t)256 * SLOT, Wfc, bfc, out);
}